// Round 4
// baseline (103552.795 us; speedup 1.0000x reference)
//
#include <hip/hip_runtime.h>
#include <math.h>

#define NB 64
#define ND 2048
#define NE 512
#define NM 25
#define NOUT 4096
#define NHEADS 8
#define NDH 64
#define NS 64
#define NITER 50
#define NKSYN 2560
#define NWG 256
#define PRED_TOTAL (NB * NOUT * NITER)   /* 13107200 */

typedef unsigned short bf16_t;

__device__ __forceinline__ float sigm(float x) { return 1.f / (1.f + expf(-x)); }

__device__ __forceinline__ bf16_t f2bf(float f) {
    unsigned u = __float_as_uint(f);
    unsigned r = (u + 0x7FFFu + ((u >> 16) & 1u)) >> 16;
    return (bf16_t)r;
}
__device__ __forceinline__ float bf2f(bf16_t h) {
    return __uint_as_float(((unsigned)h) << 16);
}

__device__ __forceinline__ float wredsum(float v) {
#pragma unroll
    for (int o = 32; o; o >>= 1) v += __shfl_xor(v, o);
    return v;
}
__device__ __forceinline__ float wredmax(float v) {
#pragma unroll
    for (int o = 32; o; o >>= 1) v = fmaxf(v, __shfl_xor(v, o));
    return v;
}

// OP: 0 = sum, 1 = max. red must hold >= blockDim.x/64 floats.
template <int OP>
__device__ __forceinline__ float blockReduce(float v, float* red) {
    const int tid = threadIdx.x, lane = tid & 63, wid = tid >> 6;
    v = (OP == 0) ? wredsum(v) : wredmax(v);
    __syncthreads();
    if (lane == 0) red[wid] = v;
    __syncthreads();
    if (tid == 0) {
        const int nw = blockDim.x >> 6;
        float r = red[0];
        for (int w = 1; w < nw; ++w) r = (OP == 0) ? r + red[w] : fmaxf(r, red[w]);
        red[0] = r;
    }
    __syncthreads();
    return red[0];
}

// software grid barrier: monotone counter, device-scope atomics.
// all NWG blocks must execute the same sequence of gsync calls.
// barCnt MUST be zeroed before launch (k_init_state does this every call).
__device__ __forceinline__ void gsync(unsigned* cnt, unsigned* nbar) {
    __syncthreads();
    if (threadIdx.x == 0) {
        __threadfence();
        __hip_atomic_fetch_add(cnt, 1u, __ATOMIC_RELEASE, __HIP_MEMORY_SCOPE_AGENT);
        const unsigned tgt = ++(*nbar) * NWG;
        while (__hip_atomic_load(cnt, __ATOMIC_ACQUIRE, __HIP_MEMORY_SCOPE_AGENT) < tgt) {
            __builtin_amdgcn_s_sleep(1);
        }
        __threadfence();
    }
    __syncthreads();
}

// ---------------- parameter struct for the persistent kernel ----------------
struct CtmP {
    const float *W_qq, *b_qq, *r_a, *r_o;
    const bf16_t *kp_t, *vp_t;
    const float *syn_w, *syn_b, *syn_ln_g, *syn_ln_b;
    const float *w1t, *b1, *w2t, *b2;
    const float *out_w, *out_b, *wo, *bo;
    const int *ial, *iar, *iol, *ior;
    float *preT, *aA, *bA, *aO, *bO;
    float *trace2, *part, *predTemp, *out;
    unsigned *barCnt;
    int tmode;
};

// P6: reduce out partials, log-softmax entropy, store predictions+certainty.
__device__ void p6_phase(const CtmP& P, int b, int tt, float* lds) {
    const int t = threadIdx.x;
    float pr[16];
    float lmax = -1e30f;
#pragma unroll
    for (int c = 0; c < 16; ++c) {
        const int j = t + c * 256;
        float v = P.out_b[j];
#pragma unroll
        for (int kp = 0; kp < 8; ++kp) v += P.part[((size_t)(kp * NB + b)) * NOUT + j];
        pr[c] = v;
        lmax = fmaxf(lmax, v);
    }
    float* red = lds + 4096;
    const float mx = blockReduce<1>(lmax, red);
    float ls = 0.f;
#pragma unroll
    for (int c = 0; c < 16; ++c) ls += expf(pr[c] - mx);
    const float se = blockReduce<0>(ls, red);
    const float logZ = mx + logf(se);
    float le = 0.f;
#pragma unroll
    for (int c = 0; c < 16; ++c) { const float lp = pr[c] - logZ; le += expf(lp) * lp; }
    const float ent = blockReduce<0>(le, red);
    const float ne = -ent * 0.12022458674074694f;  // 1/ln(4096)
    if (P.tmode) {
#pragma unroll
        for (int c = 0; c < 16; ++c)
            P.predTemp[((size_t)b * NITER + tt) * NOUT + t + c * 256] = pr[c];
    } else {
#pragma unroll
        for (int c = 0; c < 16; ++c) {
            const int j = t + c * 256;
            P.out[((size_t)b * NOUT + j) * NITER + tt] = pr[c];
        }
    }
    if (t == 0) {
        P.out[PRED_TOTAL + b * 100 + tt] = ne;
        P.out[PRED_TOTAL + b * 100 + 50 + tt] = 1.f - ne;
    }
}

// ---------------- the persistent kernel (software grid barrier) ----------------
// 256 wg x 256 threads. 5 grid syncs per iteration.
__global__ __launch_bounds__(256) void ctm_loop(CtmP P) {
    __shared__ float lds[4160];
    const int wg = blockIdx.x;
    const int t = threadIdx.x;
    const int lane = t & 63;
    const int wv = t >> 6;
    unsigned nbar = 0;

    for (int it = 0; it < NITER; ++it) {
        // ---- slot A: P0 front (wg<64) || P6 for it-1 (64<=wg<128) ----
        if (wg < 64) {
            const int b = wg;
            float* syncS = lds;
            float* qhS = lds + 512;
            float* attnS = lds + 1024;
            float* oS = lds + 1536;
            // action sync (stateful update)
#pragma unroll
            for (int c = 0; c < 2; ++c) {
                const int i = t + c * 256;
                const float pl = P.preT[(NE + P.ial[i]) * NB + b];
                const float prr = P.preT[(NE + P.iar[i]) * NB + b];
                const float r = P.r_a[i];
                const float aN = r * P.aA[b * NE + i] + pl * prr;
                const float bN = r * P.bA[b * NE + i] + 1.f;
                P.aA[b * NE + i] = aN;
                P.bA[b * NE + i] = bN;
                syncS[i] = aN * rsqrtf(bN);
            }
            __syncthreads();
            // qh = sync @ W_qq + b_qq
#pragma unroll
            for (int c = 0; c < 2; ++c) {
                const int j = t + c * 256;
                float acc = P.b_qq[j];
                for (int k = 0; k < NE; k += 4) {
                    const float4 s4 = *(const float4*)(syncS + k);
                    acc = fmaf(s4.x, P.W_qq[(k + 0) * NE + j], acc);
                    acc = fmaf(s4.y, P.W_qq[(k + 1) * NE + j], acc);
                    acc = fmaf(s4.z, P.W_qq[(k + 2) * NE + j], acc);
                    acc = fmaf(s4.w, P.W_qq[(k + 3) * NE + j], acc);
                }
                qhS[j] = acc;
            }
            __syncthreads();
            // scores + softmax: wave handles one head, lanes = s
#pragma unroll
            for (int c = 0; c < 2; ++c) {
                const int h = wv + 4 * c, s = lane;
                const bf16_t* kpp = P.kp_t + ((size_t)(b * NHEADS + h) * NDH) * NS + s;
                float sc = 0.f;
                for (int d = 0; d < NDH; ++d) sc = fmaf(qhS[h * NDH + d], bf2f(kpp[d * NS]), sc);
                sc *= 0.125f;
                const float mxv = wredmax(sc);
                const float ev = expf(sc - mxv);
                const float sm = wredsum(ev);
                attnS[h * NS + s] = ev / sm;
            }
            __syncthreads();
            // o = attn @ V
#pragma unroll
            for (int c = 0; c < 2; ++c) {
                const int h = wv + 4 * c, d = lane;
                const bf16_t* vpp = P.vp_t + ((size_t)(b * NHEADS + h) * NS) * NDH + d;
                float o = 0.f;
                for (int s2 = 0; s2 < NS; ++s2) o = fmaf(attnS[h * NS + s2], bf2f(vpp[s2 * NDH]), o);
                oS[h * NDH + d] = o;
            }
            __syncthreads();
            // attn_out = o @ wo + bo -> preT rows [0,512)
#pragma unroll
            for (int c = 0; c < 2; ++c) {
                const int j = t + c * 256;
                float ao = P.bo[j];
                for (int e = 0; e < NE; e += 4) {
                    const float4 o4 = *(const float4*)(oS + e);
                    ao = fmaf(o4.x, P.wo[(e + 0) * NE + j], ao);
                    ao = fmaf(o4.y, P.wo[(e + 1) * NE + j], ao);
                    ao = fmaf(o4.z, P.wo[(e + 2) * NE + j], ao);
                    ao = fmaf(o4.w, P.wo[(e + 3) * NE + j], ao);
                }
                P.preT[j * NB + b] = ao;
            }
        } else if (wg < 128 && it > 0) {
            p6_phase(P, wg - 64, it - 1, lds);
        }
        gsync(P.barCnt, &nbar);

        // ---- P1: syn GEMM (all wg). kp (8) x jt (32), K-slice 320, j-tile 128.
        {
            const int kp = wg >> 5, jt = wg & 31;
            const int j = jt * 128 + (t & 127);
            const int b0 = (t >> 7) * 32;
            float acc[32];
#pragma unroll
            for (int c = 0; c < 32; ++c) acc[c] = 0.f;
            const int k0 = kp * 320;
            for (int k = k0; k < k0 + 320; ++k) {
                const float w = P.syn_w[(size_t)k * NOUT + j];
                const float4* pb = (const float4*)(P.preT + k * NB + b0);
#pragma unroll
                for (int q = 0; q < 8; ++q) {
                    const float4 p4 = pb[q];
                    acc[q * 4 + 0] = fmaf(p4.x, w, acc[q * 4 + 0]);
                    acc[q * 4 + 1] = fmaf(p4.y, w, acc[q * 4 + 1]);
                    acc[q * 4 + 2] = fmaf(p4.z, w, acc[q * 4 + 2]);
                    acc[q * 4 + 3] = fmaf(p4.w, w, acc[q * 4 + 3]);
                }
            }
#pragma unroll
            for (int c = 0; c < 32; ++c)
                P.part[((size_t)(kp * NB + b0 + c)) * NOUT + j] = acc[c];
        }
        gsync(P.barCnt, &nbar);

        // ---- P2: reduce partials + GLU + LN -> trace2[pos] (wg<64) ----
        if (wg < 64) {
            const int b = wg;
            const int pos = it % NM;
            float g[8];
            float ssum = 0.f;
#pragma unroll
            for (int c = 0; c < 8; ++c) {
                const int n = t + c * 256;
                float ya = P.syn_b[n], yb = P.syn_b[n + ND];
#pragma unroll
                for (int kp = 0; kp < 8; ++kp) {
                    ya += P.part[((size_t)(kp * NB + b)) * NOUT + n];
                    yb += P.part[((size_t)(kp * NB + b)) * NOUT + n + ND];
                }
                g[c] = ya * sigm(yb);
                ssum += g[c];
            }
            float* red = lds + 4096;
            const float mean = blockReduce<0>(ssum, red) * (1.f / ND);
            float vsum = 0.f;
#pragma unroll
            for (int c = 0; c < 8; ++c) { const float d = g[c] - mean; vsum += d * d; }
            const float var = blockReduce<0>(vsum, red) * (1.f / ND);
            const float rs = rsqrtf(var + 1e-5f);
#pragma unroll
            for (int c = 0; c < 8; ++c) {
                const int n = t + c * 256;
                const float st = (g[c] - mean) * rs * P.syn_ln_g[n] + P.syn_ln_b[n];
                P.trace2[((size_t)pos * ND + n) * NB + b] = st;
            }
        }
        gsync(P.barCnt, &nbar);

        // ---- P3: per-neuron NLMs -> act (all wg). lane=b, acc over 64 hh. ----
        {
            const int pos = it % NM;
            const int b = lane;
#pragma unroll 1
            for (int sub = 0; sub < 2; ++sub) {
                const int n = wg * 8 + wv * 2 + sub;
                float acc[64];
                const float4* b14 = (const float4*)(P.b1 + n * 64);
#pragma unroll
                for (int q = 0; q < 16; ++q) {
                    const float4 v = b14[q];
                    acc[q * 4 + 0] = v.x; acc[q * 4 + 1] = v.y;
                    acc[q * 4 + 2] = v.z; acc[q * 4 + 3] = v.w;
                }
#pragma unroll 1
                for (int m = 0; m < NM; ++m) {
                    int phys = pos + 1 + m;
                    if (phys >= NM) phys -= NM;
                    const float tr = P.trace2[((size_t)phys * ND + n) * NB + b];
                    const float4* w4 = (const float4*)(P.w1t + ((size_t)n * NM + m) * 64);
#pragma unroll
                    for (int q = 0; q < 16; ++q) {
                        const float4 v = w4[q];
                        acc[q * 4 + 0] = fmaf(tr, v.x, acc[q * 4 + 0]);
                        acc[q * 4 + 1] = fmaf(tr, v.y, acc[q * 4 + 1]);
                        acc[q * 4 + 2] = fmaf(tr, v.z, acc[q * 4 + 2]);
                        acc[q * 4 + 3] = fmaf(tr, v.w, acc[q * 4 + 3]);
                    }
                }
                float z0 = P.b2[n * 2 + 0], z1 = P.b2[n * 2 + 1];
                const float* w2r = P.w2t + n * 64;
#pragma unroll
                for (int i = 0; i < 32; ++i) {
                    const float hv = acc[i] * sigm(acc[32 + i]);
                    z0 = fmaf(hv, w2r[i], z0);
                    z1 = fmaf(hv, w2r[32 + i], z1);
                }
                P.preT[(NE + n) * NB + b] = z0 * sigm(z1);
            }
        }
        gsync(P.barCnt, &nbar);

        // ---- P5: output sync (fused, double-buffered aO/bO) + out GEMM ----
        {
            const int kp = wg >> 5, jt = wg & 31;
            const int src = it & 1, dst = src ^ 1;
            float* syncL = lds;  // [64 i][64 b]
#pragma unroll
            for (int c = 0; c < 16; ++c) {
                const int idx = t + c * 256;
                const int il = idx >> 6, b = idx & 63;
                const int i = kp * 64 + il;
                const float pl = P.preT[(NE + P.iol[i]) * NB + b];
                const float prr = P.preT[(NE + P.ior[i]) * NB + b];
                const float r = P.r_o[i];
                const float aN = r * P.aO[src * 32768 + i * NB + b] + pl * prr;
                const float bN = r * P.bO[src * 32768 + i * NB + b] + 1.f;
                if (jt == 0) {
                    P.aO[dst * 32768 + i * NB + b] = aN;
                    P.bO[dst * 32768 + i * NB + b] = bN;
                }
                syncL[il * 64 + b] = aN * rsqrtf(bN);
            }
            __syncthreads();
            const int j = jt * 128 + (t & 127);
            const int b0 = (t >> 7) * 32;
            float acc[32];
#pragma unroll
            for (int c = 0; c < 32; ++c) acc[c] = 0.f;
            for (int k = 0; k < 64; ++k) {
                const float w = P.out_w[(size_t)(kp * 64 + k) * NOUT + j];
                const float4* sb = (const float4*)(syncL + k * 64 + b0);
#pragma unroll
                for (int q = 0; q < 8; ++q) {
                    const float4 s4 = sb[q];
                    acc[q * 4 + 0] = fmaf(s4.x, w, acc[q * 4 + 0]);
                    acc[q * 4 + 1] = fmaf(s4.y, w, acc[q * 4 + 1]);
                    acc[q * 4 + 2] = fmaf(s4.z, w, acc[q * 4 + 2]);
                    acc[q * 4 + 3] = fmaf(s4.w, w, acc[q * 4 + 3]);
                }
            }
#pragma unroll
            for (int c = 0; c < 32; ++c)
                P.part[((size_t)(kp * NB + b0 + c)) * NOUT + j] = acc[c];
        }
        gsync(P.barCnt, &nbar);
    }
    // final P6 (tt = 49)
    if (wg >= 64 && wg < 128) p6_phase(P, wg - 64, NITER - 1, lds);
}

// ---------------- one-time precompute kernels ----------------

__global__ __launch_bounds__(512) void k_p0(const float* __restrict__ dec_a,
                                            const float* __restrict__ dec_o,
                                            const float* __restrict__ q_b,
                                            const float* __restrict__ wq,
                                            const float* __restrict__ bq,
                                            float* __restrict__ r_a, float* __restrict__ r_o,
                                            float* __restrict__ b_qq) {
    const int t = threadIdx.x;
    r_a[t] = expf(-fminf(fmaxf(dec_a[t], 0.f), 15.f));
    r_o[t] = expf(-fminf(fmaxf(dec_o[t], 0.f), 15.f));
    float acc = bq[t];
    for (int k = 0; k < NE; ++k) acc = fmaf(q_b[k], wq[k * NE + t], acc);
    b_qq[t] = acc;
}

__global__ __launch_bounds__(256) void k_wqq(const float* __restrict__ q_w,
                                             const float* __restrict__ wq,
                                             float* __restrict__ W_qq) {
    const int idx = blockIdx.x * 256 + threadIdx.x;
    const int r = idx >> 9, c = idx & 511;
    float acc = 0.f;
    for (int k = 0; k < NE; ++k) acc = fmaf(q_w[r * NE + k], wq[k * NE + c], acc);
    W_qq[idx] = acc;
}

// trace2[m][n][b] = start_trace[n][m]
__global__ __launch_bounds__(256) void k_init_trace2(const float* __restrict__ st,
                                                     float* __restrict__ trace2) {
    const int idx = blockIdx.x * 256 + threadIdx.x;
    const int n = (idx >> 6) & (ND - 1);
    const int m = idx >> 17;
    trace2[idx] = st[n * NM + m];
}

// act init into preT rows [512,2560) + zero aA,bA,aO(x2),bO(x2)+barCnt contiguous span.
// FIX (round 3 post-mortem): grid was floor-divided, leaving the last 64 floats
// (the barrier counter!) unzeroed -> 0xAA poison -> all grid barriers fell
// through instantly -> racing phases. Now ceil-divided with a bound guard.
#define INIT_TOTAL (NB * ND + 6 * NB * NE + 64)
__global__ __launch_bounds__(256) void k_init_state(const float* __restrict__ sa,
                                                    float* __restrict__ preT,
                                                    float* __restrict__ zeroBase) {
    const int idx = blockIdx.x * 256 + threadIdx.x;
    if (idx >= INIT_TOTAL) return;
    if (idx < NB * ND) {
        const int b = idx & 63, n = idx >> 6;
        preT[(NE + n) * NB + b] = sa[n];
    } else {
        zeroBase[idx - NB * ND] = 0.f;
    }
}

// kv = LN(feats @ kv_w + kv_b); K/V projections -> bf16 caches
__global__ __launch_bounds__(512) void k_p1(const float* __restrict__ x,
                                            const float* __restrict__ kv_w,
                                            const float* __restrict__ kv_b,
                                            const float* __restrict__ ln_g,
                                            const float* __restrict__ ln_b,
                                            const float* __restrict__ wk,
                                            const float* __restrict__ bk,
                                            const float* __restrict__ wv,
                                            const float* __restrict__ bv,
                                            bf16_t* __restrict__ kp_t,
                                            bf16_t* __restrict__ vp_t) {
    __shared__ float kvS[NE];
    __shared__ float red[8];
    const int b = blockIdx.x >> 6, s = blockIdx.x & 63;
    const int e = threadIdx.x;
    float acc = kv_b[e];
#pragma unroll
    for (int c = 0; c < 12; ++c) acc = fmaf(x[b * 768 + c * 64 + s], kv_w[c * NE + e], acc);
    const float m = blockReduce<0>(acc, red) * (1.f / NE);
    const float d = acc - m;
    const float v = blockReduce<0>(d * d, red) * (1.f / NE);
    kvS[e] = d * rsqrtf(v + 1e-5f) * ln_g[e] + ln_b[e];
    __syncthreads();
    const int j = e;
    float kpv = bk[j], vpv = bv[j];
    for (int k = 0; k < NE; k += 4) {
        const float4 kv4 = *(const float4*)(kvS + k);
        kpv = fmaf(kv4.x, wk[(k + 0) * NE + j], kpv);
        kpv = fmaf(kv4.y, wk[(k + 1) * NE + j], kpv);
        kpv = fmaf(kv4.z, wk[(k + 2) * NE + j], kpv);
        kpv = fmaf(kv4.w, wk[(k + 3) * NE + j], kpv);
        vpv = fmaf(kv4.x, wv[(k + 0) * NE + j], vpv);
        vpv = fmaf(kv4.y, wv[(k + 1) * NE + j], vpv);
        vpv = fmaf(kv4.z, wv[(k + 2) * NE + j], vpv);
        vpv = fmaf(kv4.w, wv[(k + 3) * NE + j], vpv);
    }
    const int h = j >> 6, dd = j & 63;
    kp_t[((size_t)(b * NHEADS + h) * NDH + dd) * NS + s] = f2bf(kpv);
    vp_t[((size_t)(b * NHEADS + h) * NS + s) * NDH + dd] = f2bf(vpv);
}

// w1 (25,64,2048) -> w1t[n][m][hh]
__global__ __launch_bounds__(256) void k_w1t(const float* __restrict__ w1,
                                             float* __restrict__ w1t) {
    const int idx = blockIdx.x * 256 + threadIdx.x;
    const int hh = idx & 63;
    const int m = (idx >> 6) % NM;
    const int n = idx / (NM * 64);
    w1t[idx] = w1[(size_t)(m * 64 + hh) * ND + n];
}

// w2 (32,2,2048) -> w2t[n][c*32+i]
__global__ __launch_bounds__(256) void k_w2t(const float* __restrict__ w2,
                                             float* __restrict__ w2t) {
    const int idx = blockIdx.x * 256 + threadIdx.x;
    const int i = idx & 31;
    const int c = (idx >> 5) & 1;
    const int n = idx >> 6;
    w2t[idx] = w2[(size_t)(i * 2 + c) * ND + n];
}

// predTemp (B,T,O) -> out (B,O,T)
__global__ __launch_bounds__(256) void k_transpose(const float* __restrict__ predTemp,
                                                   float* __restrict__ out) {
    __shared__ float tile[NS * NITER];
    const int b = blockIdx.x >> 6;
    const int j0 = (blockIdx.x & 63) * 64;
    for (int i = threadIdx.x; i < 3200; i += 256) {
        const int tt = i >> 6, jj = i & 63;
        tile[jj * NITER + tt] = predTemp[((size_t)b * NITER + tt) * NOUT + j0 + jj];
    }
    __syncthreads();
    float* dst = out + ((size_t)b * NOUT + j0) * NITER;
    for (int i = threadIdx.x; i < 3200; i += 256) dst[i] = tile[i];
}

extern "C" void kernel_launch(void* const* d_in, const int* in_sizes, int n_in,
                              void* d_out, int out_size, void* d_ws, size_t ws_size,
                              hipStream_t stream) {
    const float* x        = (const float*)d_in[0];
    const float* kv_w     = (const float*)d_in[1];
    const float* kv_b     = (const float*)d_in[2];
    const float* kv_ln_g  = (const float*)d_in[3];
    const float* kv_ln_b  = (const float*)d_in[4];
    const float* q_w      = (const float*)d_in[5];
    const float* q_b      = (const float*)d_in[6];
    const float* wq       = (const float*)d_in[7];
    const float* wk       = (const float*)d_in[8];
    const float* wv       = (const float*)d_in[9];
    const float* wo       = (const float*)d_in[10];
    const float* bq       = (const float*)d_in[11];
    const float* bk       = (const float*)d_in[12];
    const float* bv       = (const float*)d_in[13];
    const float* bo       = (const float*)d_in[14];
    const float* syn_w    = (const float*)d_in[15];
    const float* syn_b    = (const float*)d_in[16];
    const float* syn_ln_g = (const float*)d_in[17];
    const float* syn_ln_b = (const float*)d_in[18];
    const float* nlm1_w   = (const float*)d_in[19];
    const float* nlm1_b   = (const float*)d_in[20];
    const float* nlm2_w   = (const float*)d_in[21];
    const float* nlm2_b   = (const float*)d_in[22];
    const float* start_a  = (const float*)d_in[23];
    const float* start_tr = (const float*)d_in[24];
    const float* dec_a    = (const float*)d_in[25];
    const float* dec_o    = (const float*)d_in[26];
    const float* out_w    = (const float*)d_in[27];
    const float* out_b    = (const float*)d_in[28];
    const int* ial        = (const int*)d_in[29];
    const int* iar        = (const int*)d_in[30];
    const int* iol        = (const int*)d_in[31];
    const int* ior        = (const int*)d_in[32];
    float* out = (float*)d_out;

    float* ws = (float*)d_ws;
    size_t off = 0;
    auto alloc = [&](size_t n) { float* p = ws + off; off += n; return p; };
    float* preT   = alloc((size_t)NKSYN * NB);          // 163840
    bf16_t* kp_t  = (bf16_t*)alloc((size_t)NB * NE * NS / 2);  // 1048576 f-slots
    bf16_t* vp_t  = (bf16_t*)alloc((size_t)NB * NE * NS / 2);
    float* W_qq   = alloc((size_t)NE * NE);             // 262144
    float* b_qq   = alloc(NE);
    float* r_a    = alloc(NE);
    float* r_o    = alloc(NE);
    float* aA     = alloc((size_t)NB * NE);             // zero span start
    float* bA     = alloc((size_t)NB * NE);
    float* aO     = alloc((size_t)2 * NB * NE);         // double-buffered
    float* bO     = alloc((size_t)2 * NB * NE);
    float* barMem = alloc(64);                          // barrier counter (zeroed)
    float* trace2 = alloc((size_t)NM * ND * NB);        // 3276800
    float* part   = alloc((size_t)8 * NB * NOUT);       // 2097152 (shared syn/out)
    float* w1t    = alloc((size_t)ND * NM * 64);        // 3276800
    float* w2t    = alloc((size_t)ND * 64);             // 131072
    int tmode = 0;
    float* predTemp = nullptr;
    if ((off + (size_t)PRED_TOTAL) * sizeof(float) <= ws_size) {
        predTemp = alloc((size_t)PRED_TOTAL);
        tmode = 1;
    }

    k_p0<<<1, 512, 0, stream>>>(dec_a, dec_o, q_b, wq, bq, r_a, r_o, b_qq);
    k_wqq<<<1024, 256, 0, stream>>>(q_w, wq, W_qq);
    k_init_trace2<<<(NM * ND * NB) / 256, 256, 0, stream>>>(start_tr, trace2);
    // zero span: aA, bA, aO(x2), bO(x2), barCnt -- ceil-divided grid (see fix note)
    k_init_state<<<(INIT_TOTAL + 255) / 256, 256, 0, stream>>>(start_a, preT, aA);
    k_p1<<<NB * NS, 512, 0, stream>>>(x, kv_w, kv_b, kv_ln_g, kv_ln_b, wk, bk, wv, bv, kp_t, vp_t);
    k_w1t<<<(ND * NM * 64) / 256, 256, 0, stream>>>(nlm1_w, w1t);
    k_w2t<<<(ND * 64) / 256, 256, 0, stream>>>(nlm2_w, w2t);

    CtmP cp;
    cp.W_qq = W_qq; cp.b_qq = b_qq; cp.r_a = r_a; cp.r_o = r_o;
    cp.kp_t = kp_t; cp.vp_t = vp_t;
    cp.syn_w = syn_w; cp.syn_b = syn_b; cp.syn_ln_g = syn_ln_g; cp.syn_ln_b = syn_ln_b;
    cp.w1t = w1t; cp.b1 = nlm1_b; cp.w2t = w2t; cp.b2 = nlm2_b;
    cp.out_w = out_w; cp.out_b = out_b; cp.wo = wo; cp.bo = bo;
    cp.ial = ial; cp.iar = iar; cp.iol = iol; cp.ior = ior;
    cp.preT = preT; cp.aA = aA; cp.bA = bA; cp.aO = aO; cp.bO = bO;
    cp.trace2 = trace2; cp.part = part; cp.predTemp = predTemp; cp.out = out;
    cp.barCnt = (unsigned*)barMem;
    cp.tmode = tmode;
    ctm_loop<<<NWG, 256, 0, stream>>>(cp);

    if (tmode) k_transpose<<<NB * 64, 256, 0, stream>>>(predTemp, out);
}

// Round 5
// 13445.981 us; speedup vs baseline: 7.7014x; 7.7014x over previous
//
#include <hip/hip_runtime.h>
#include <math.h>

#define NB 64
#define ND 2048
#define NE 512
#define NM 25
#define NOUT 4096
#define NHEADS 8
#define NDH 64
#define NS 64
#define NITER 50
#define NKSYN 2560
#define PRED_TOTAL (NB * NOUT * NITER)   /* 13107200 */

typedef unsigned short bf16_t;

__device__ __forceinline__ float sigm(float x) { return 1.f / (1.f + expf(-x)); }

__device__ __forceinline__ bf16_t f2bf(float f) {
    unsigned u = __float_as_uint(f);
    unsigned r = (u + 0x7FFFu + ((u >> 16) & 1u)) >> 16;
    return (bf16_t)r;
}
__device__ __forceinline__ float bf2f(bf16_t h) {
    return __uint_as_float(((unsigned)h) << 16);
}

__device__ __forceinline__ float wredsum(float v) {
#pragma unroll
    for (int o = 32; o; o >>= 1) v += __shfl_xor(v, o);
    return v;
}
__device__ __forceinline__ float wredmax(float v) {
#pragma unroll
    for (int o = 32; o; o >>= 1) v = fmaxf(v, __shfl_xor(v, o));
    return v;
}

// OP: 0 = sum, 1 = max. red must hold >= blockDim.x/64 floats.
template <int OP>
__device__ __forceinline__ float blockReduce(float v, float* red) {
    const int tid = threadIdx.x, lane = tid & 63, wid = tid >> 6;
    v = (OP == 0) ? wredsum(v) : wredmax(v);
    __syncthreads();
    if (lane == 0) red[wid] = v;
    __syncthreads();
    if (tid == 0) {
        const int nw = blockDim.x >> 6;
        float r = red[0];
        for (int w = 1; w < nw; ++w) r = (OP == 0) ? r + red[w] : fmaxf(r, red[w]);
        red[0] = r;
    }
    __syncthreads();
    return red[0];
}

// ---------------- per-step kernels (separate dispatches; CP does the barrier) ----------

// KA: [optional] final(tt) for prev step + front(it). grid 64 (b) x 512.
// front: action sync -> qh=sync@W_qq -> attention (bf16 K/V) -> attn_out -> preT[0..512)
// final: reduce out partials + log-softmax entropy -> predictions + certainty
__global__ __launch_bounds__(512) void k_front_final(
        float* __restrict__ preT, float* __restrict__ aA, float* __restrict__ bA,
        const float* __restrict__ r_a,
        const int* __restrict__ ial, const int* __restrict__ iar,
        const float* __restrict__ W_qq, const float* __restrict__ b_qq,
        const bf16_t* __restrict__ kp_t, const bf16_t* __restrict__ vp_t,
        const float* __restrict__ wo, const float* __restrict__ bo,
        const float* __restrict__ part, const float* __restrict__ out_b,
        float* __restrict__ out, float* __restrict__ predTemp,
        int doFront, int doFinal, int tt, int tmode) {
    __shared__ float lds[2056];
    const int b = blockIdx.x;
    const int t = threadIdx.x;
    const int lane = t & 63, wv = t >> 6;
    float* red = lds + 2048;

    if (doFinal) {
        float pr[8];
        float lmax = -1e30f;
#pragma unroll
        for (int c = 0; c < 8; ++c) {
            const int j = t + c * 512;
            float v = out_b[j];
#pragma unroll
            for (int kp = 0; kp < 8; ++kp) v += part[((size_t)(kp * NB + b)) * NOUT + j];
            pr[c] = v;
            lmax = fmaxf(lmax, v);
        }
        const float mx = blockReduce<1>(lmax, red);
        float ls = 0.f;
#pragma unroll
        for (int c = 0; c < 8; ++c) ls += expf(pr[c] - mx);
        const float se = blockReduce<0>(ls, red);
        const float logZ = mx + logf(se);
        float le = 0.f;
#pragma unroll
        for (int c = 0; c < 8; ++c) { const float lp = pr[c] - logZ; le += expf(lp) * lp; }
        const float ent = blockReduce<0>(le, red);
        const float ne = -ent * 0.12022458674074694f;  // 1/ln(4096)
        if (tmode) {
#pragma unroll
            for (int c = 0; c < 8; ++c)
                predTemp[((size_t)b * NITER + tt) * NOUT + t + c * 512] = pr[c];
        } else {
#pragma unroll
            for (int c = 0; c < 8; ++c) {
                const int j = t + c * 512;
                out[((size_t)b * NOUT + j) * NITER + tt] = pr[c];
            }
        }
        if (t == 0) {
            out[PRED_TOTAL + b * 100 + tt] = ne;
            out[PRED_TOTAL + b * 100 + 50 + tt] = 1.f - ne;
        }
    }

    if (doFront) {
        float* syncS = lds;
        float* qhS = lds + 512;
        float* attnS = lds + 1024;
        float* oS = lds + 1536;
        if (doFinal) __syncthreads();
        // phase 1: action sync (stateful)
        {
            const int i = t;
            const float pl = preT[(NE + ial[i]) * NB + b];
            const float prr = preT[(NE + iar[i]) * NB + b];
            const float r = r_a[i];
            const float aN = r * aA[b * NE + i] + pl * prr;
            const float bN = r * bA[b * NE + i] + 1.f;
            aA[b * NE + i] = aN;
            bA[b * NE + i] = bN;
            syncS[i] = aN * rsqrtf(bN);
        }
        __syncthreads();
        // phase 2: qh = sync @ W_qq + b_qq
        {
            const int j = t;
            float acc = b_qq[j];
            for (int k = 0; k < NE; k += 4) {
                const float4 s4 = *(const float4*)(syncS + k);
                acc = fmaf(s4.x, W_qq[(k + 0) * NE + j], acc);
                acc = fmaf(s4.y, W_qq[(k + 1) * NE + j], acc);
                acc = fmaf(s4.z, W_qq[(k + 2) * NE + j], acc);
                acc = fmaf(s4.w, W_qq[(k + 3) * NE + j], acc);
            }
            qhS[j] = acc;
        }
        __syncthreads();
        // phase 3: scores + softmax (wave per head, lanes = s)
        {
            const int h = wv, s = lane;
            const bf16_t* kpp = kp_t + ((size_t)(b * NHEADS + h) * NDH) * NS + s;
            float sc = 0.f;
            for (int d = 0; d < NDH; ++d) sc = fmaf(qhS[h * NDH + d], bf2f(kpp[d * NS]), sc);
            sc *= 0.125f;
            const float mxv = wredmax(sc);
            const float ev = expf(sc - mxv);
            const float sm = wredsum(ev);
            attnS[h * NS + s] = ev / sm;
        }
        __syncthreads();
        // phase 4: o = attn @ V
        {
            const int h = wv, d = lane;
            const bf16_t* vpp = vp_t + ((size_t)(b * NHEADS + h) * NS) * NDH + d;
            float o = 0.f;
            for (int s2 = 0; s2 < NS; ++s2) o = fmaf(attnS[h * NS + s2], bf2f(vpp[s2 * NDH]), o);
            oS[h * NDH + d] = o;
        }
        __syncthreads();
        // phase 5: attn_out = o @ wo + bo -> preT rows [0,512)
        {
            const int j = t;
            float ao = bo[j];
            for (int e = 0; e < NE; e += 4) {
                const float4 o4 = *(const float4*)(oS + e);
                ao = fmaf(o4.x, wo[(e + 0) * NE + j], ao);
                ao = fmaf(o4.y, wo[(e + 1) * NE + j], ao);
                ao = fmaf(o4.z, wo[(e + 2) * NE + j], ao);
                ao = fmaf(o4.w, wo[(e + 3) * NE + j], ao);
            }
            preT[j * NB + b] = ao;
        }
    }
}

// KB: syn GEMM partials. grid 256 (kp=bid>>5, jt=bid&31) x 256.
__global__ __launch_bounds__(256) void k_gemm_syn(const float* __restrict__ preT,
                                                  const float* __restrict__ syn_w,
                                                  float* __restrict__ part) {
    const int kp = blockIdx.x >> 5, jt = blockIdx.x & 31;
    const int j = jt * 128 + (threadIdx.x & 127);
    const int b0 = (threadIdx.x >> 7) * 32;
    float acc[32];
#pragma unroll
    for (int c = 0; c < 32; ++c) acc[c] = 0.f;
    const int k0 = kp * 320;
    for (int k = k0; k < k0 + 320; ++k) {
        const float w = syn_w[(size_t)k * NOUT + j];
        const float4* pb = (const float4*)(preT + k * NB + b0);
#pragma unroll
        for (int q = 0; q < 8; ++q) {
            const float4 p4 = pb[q];
            acc[q * 4 + 0] = fmaf(p4.x, w, acc[q * 4 + 0]);
            acc[q * 4 + 1] = fmaf(p4.y, w, acc[q * 4 + 1]);
            acc[q * 4 + 2] = fmaf(p4.z, w, acc[q * 4 + 2]);
            acc[q * 4 + 3] = fmaf(p4.w, w, acc[q * 4 + 3]);
        }
    }
#pragma unroll
    for (int c = 0; c < 32; ++c)
        part[((size_t)(kp * NB + b0 + c)) * NOUT + j] = acc[c];
}

// KC: reduce partials + GLU + LN -> trace2[pos]. grid 64 (b) x 256.
__global__ __launch_bounds__(256) void k_glu_ln(const float* __restrict__ part,
                                                const float* __restrict__ syn_b,
                                                const float* __restrict__ ln_g,
                                                const float* __restrict__ ln_b,
                                                float* __restrict__ trace2, int pos) {
    __shared__ float red[8];
    const int b = blockIdx.x;
    const int t = threadIdx.x;
    float g[8];
    float ssum = 0.f;
#pragma unroll
    for (int c = 0; c < 8; ++c) {
        const int n = t + c * 256;
        float ya = syn_b[n], yb = syn_b[n + ND];
#pragma unroll
        for (int kp = 0; kp < 8; ++kp) {
            ya += part[((size_t)(kp * NB + b)) * NOUT + n];
            yb += part[((size_t)(kp * NB + b)) * NOUT + n + ND];
        }
        g[c] = ya * sigm(yb);
        ssum += g[c];
    }
    const float mean = blockReduce<0>(ssum, red) * (1.f / ND);
    float vsum = 0.f;
#pragma unroll
    for (int c = 0; c < 8; ++c) { const float d = g[c] - mean; vsum += d * d; }
    const float var = blockReduce<0>(vsum, red) * (1.f / ND);
    const float rs = rsqrtf(var + 1e-5f);
#pragma unroll
    for (int c = 0; c < 8; ++c) {
        const int n = t + c * 256;
        const float st = (g[c] - mean) * rs * ln_g[n] + ln_b[n];
        trace2[((size_t)pos * ND + n) * NB + b] = st;
    }
}

// KD: per-neuron NLMs -> act into preT rows [512,2560). grid 256 x 256. lane = b.
__global__ __launch_bounds__(256) void k_nlm(const float* __restrict__ trace2,
                                             const float* __restrict__ w1t,
                                             const float* __restrict__ b1,
                                             const float* __restrict__ w2t,
                                             const float* __restrict__ b2,
                                             float* __restrict__ preT, int pos) {
    const int b = threadIdx.x & 63;
    const int wv = threadIdx.x >> 6;
#pragma unroll 1
    for (int sub = 0; sub < 2; ++sub) {
        const int n = blockIdx.x * 8 + wv * 2 + sub;
        float acc[64];
        const float4* b14 = (const float4*)(b1 + n * 64);
#pragma unroll
        for (int q = 0; q < 16; ++q) {
            const float4 v = b14[q];
            acc[q * 4 + 0] = v.x; acc[q * 4 + 1] = v.y;
            acc[q * 4 + 2] = v.z; acc[q * 4 + 3] = v.w;
        }
#pragma unroll 1
        for (int m = 0; m < NM; ++m) {
            int phys = pos + 1 + m;
            if (phys >= NM) phys -= NM;
            const float tr = trace2[((size_t)phys * ND + n) * NB + b];
            const float4* w4 = (const float4*)(w1t + ((size_t)n * NM + m) * 64);
#pragma unroll
            for (int q = 0; q < 16; ++q) {
                const float4 v = w4[q];
                acc[q * 4 + 0] = fmaf(tr, v.x, acc[q * 4 + 0]);
                acc[q * 4 + 1] = fmaf(tr, v.y, acc[q * 4 + 1]);
                acc[q * 4 + 2] = fmaf(tr, v.z, acc[q * 4 + 2]);
                acc[q * 4 + 3] = fmaf(tr, v.w, acc[q * 4 + 3]);
            }
        }
        float z0 = b2[n * 2 + 0], z1 = b2[n * 2 + 1];
        const float* w2r = w2t + n * 64;
#pragma unroll
        for (int i = 0; i < 32; ++i) {
            const float hv = acc[i] * sigm(acc[32 + i]);
            z0 = fmaf(hv, w2r[i], z0);
            z1 = fmaf(hv, w2r[32 + i], z1);
        }
        preT[(NE + n) * NB + b] = z0 * sigm(z1);
    }
}

// KE: output sync (double-buffered aO/bO) + out GEMM partials. grid 256 x 256.
__global__ __launch_bounds__(256) void k_out(const float* __restrict__ preT,
                                             float* __restrict__ aO, float* __restrict__ bO,
                                             const float* __restrict__ r_o,
                                             const int* __restrict__ iol,
                                             const int* __restrict__ ior,
                                             const float* __restrict__ out_w,
                                             float* __restrict__ part, int it) {
    __shared__ float syncL[4096];  // [64 i][64 b]
    const int kp = blockIdx.x >> 5, jt = blockIdx.x & 31;
    const int t = threadIdx.x;
    const int src = it & 1, dst = src ^ 1;
#pragma unroll
    for (int c = 0; c < 16; ++c) {
        const int idx = t + c * 256;
        const int il = idx >> 6, b = idx & 63;
        const int i = kp * 64 + il;
        const float pl = preT[(NE + iol[i]) * NB + b];
        const float prr = preT[(NE + ior[i]) * NB + b];
        const float r = r_o[i];
        const float aN = r * aO[src * 32768 + i * NB + b] + pl * prr;
        const float bN = r * bO[src * 32768 + i * NB + b] + 1.f;
        if (jt == 0) {
            aO[dst * 32768 + i * NB + b] = aN;
            bO[dst * 32768 + i * NB + b] = bN;
        }
        syncL[il * 64 + b] = aN * rsqrtf(bN);
    }
    __syncthreads();
    const int j = jt * 128 + (t & 127);
    const int b0 = (t >> 7) * 32;
    float acc[32];
#pragma unroll
    for (int c = 0; c < 32; ++c) acc[c] = 0.f;
    for (int k = 0; k < 64; ++k) {
        const float w = out_w[(size_t)(kp * 64 + k) * NOUT + j];
        const float4* sb = (const float4*)(syncL + k * 64 + b0);
#pragma unroll
        for (int q = 0; q < 8; ++q) {
            const float4 s4 = sb[q];
            acc[q * 4 + 0] = fmaf(s4.x, w, acc[q * 4 + 0]);
            acc[q * 4 + 1] = fmaf(s4.y, w, acc[q * 4 + 1]);
            acc[q * 4 + 2] = fmaf(s4.z, w, acc[q * 4 + 2]);
            acc[q * 4 + 3] = fmaf(s4.w, w, acc[q * 4 + 3]);
        }
    }
#pragma unroll
    for (int c = 0; c < 32; ++c)
        part[((size_t)(kp * NB + b0 + c)) * NOUT + j] = acc[c];
}

// ---------------- one-time precompute kernels ----------------

__global__ __launch_bounds__(512) void k_p0(const float* __restrict__ dec_a,
                                            const float* __restrict__ dec_o,
                                            const float* __restrict__ q_b,
                                            const float* __restrict__ wq,
                                            const float* __restrict__ bq,
                                            float* __restrict__ r_a, float* __restrict__ r_o,
                                            float* __restrict__ b_qq) {
    const int t = threadIdx.x;
    r_a[t] = expf(-fminf(fmaxf(dec_a[t], 0.f), 15.f));
    r_o[t] = expf(-fminf(fmaxf(dec_o[t], 0.f), 15.f));
    float acc = bq[t];
    for (int k = 0; k < NE; ++k) acc = fmaf(q_b[k], wq[k * NE + t], acc);
    b_qq[t] = acc;
}

__global__ __launch_bounds__(256) void k_wqq(const float* __restrict__ q_w,
                                             const float* __restrict__ wq,
                                             float* __restrict__ W_qq) {
    const int idx = blockIdx.x * 256 + threadIdx.x;
    const int r = idx >> 9, c = idx & 511;
    float acc = 0.f;
    for (int k = 0; k < NE; ++k) acc = fmaf(q_w[r * NE + k], wq[k * NE + c], acc);
    W_qq[idx] = acc;
}

// trace2[m][n][b] = start_trace[n][m]
__global__ __launch_bounds__(256) void k_init_trace2(const float* __restrict__ st,
                                                     float* __restrict__ trace2) {
    const int idx = blockIdx.x * 256 + threadIdx.x;
    const int n = (idx >> 6) & (ND - 1);
    const int m = idx >> 17;
    trace2[idx] = st[n * NM + m];
}

// act init into preT rows [512,2560) + zero aA,bA,aO(x2),bO(x2) contiguous span.
#define INIT_TOTAL (NB * ND + 6 * NB * NE)
__global__ __launch_bounds__(256) void k_init_state(const float* __restrict__ sa,
                                                    float* __restrict__ preT,
                                                    float* __restrict__ zeroBase) {
    const int idx = blockIdx.x * 256 + threadIdx.x;
    if (idx >= INIT_TOTAL) return;
    if (idx < NB * ND) {
        const int b = idx & 63, n = idx >> 6;
        preT[(NE + n) * NB + b] = sa[n];
    } else {
        zeroBase[idx - NB * ND] = 0.f;
    }
}

// kv = LN(feats @ kv_w + kv_b); K/V projections -> bf16 caches
__global__ __launch_bounds__(512) void k_p1(const float* __restrict__ x,
                                            const float* __restrict__ kv_w,
                                            const float* __restrict__ kv_b,
                                            const float* __restrict__ ln_g,
                                            const float* __restrict__ ln_b,
                                            const float* __restrict__ wk,
                                            const float* __restrict__ bk,
                                            const float* __restrict__ wv,
                                            const float* __restrict__ bv,
                                            bf16_t* __restrict__ kp_t,
                                            bf16_t* __restrict__ vp_t) {
    __shared__ float kvS[NE];
    __shared__ float red[8];
    const int b = blockIdx.x >> 6, s = blockIdx.x & 63;
    const int e = threadIdx.x;
    float acc = kv_b[e];
#pragma unroll
    for (int c = 0; c < 12; ++c) acc = fmaf(x[b * 768 + c * 64 + s], kv_w[c * NE + e], acc);
    const float m = blockReduce<0>(acc, red) * (1.f / NE);
    const float d = acc - m;
    const float v = blockReduce<0>(d * d, red) * (1.f / NE);
    kvS[e] = d * rsqrtf(v + 1e-5f) * ln_g[e] + ln_b[e];
    __syncthreads();
    const int j = e;
    float kpv = bk[j], vpv = bv[j];
    for (int k = 0; k < NE; k += 4) {
        const float4 kv4 = *(const float4*)(kvS + k);
        kpv = fmaf(kv4.x, wk[(k + 0) * NE + j], kpv);
        kpv = fmaf(kv4.y, wk[(k + 1) * NE + j], kpv);
        kpv = fmaf(kv4.z, wk[(k + 2) * NE + j], kpv);
        kpv = fmaf(kv4.w, wk[(k + 3) * NE + j], kpv);
        vpv = fmaf(kv4.x, wv[(k + 0) * NE + j], vpv);
        vpv = fmaf(kv4.y, wv[(k + 1) * NE + j], vpv);
        vpv = fmaf(kv4.z, wv[(k + 2) * NE + j], vpv);
        vpv = fmaf(kv4.w, wv[(k + 3) * NE + j], vpv);
    }
    const int h = j >> 6, dd = j & 63;
    kp_t[((size_t)(b * NHEADS + h) * NDH + dd) * NS + s] = f2bf(kpv);
    vp_t[((size_t)(b * NHEADS + h) * NS + s) * NDH + dd] = f2bf(vpv);
}

// w1 (25,64,2048) -> w1t[n][m][hh]
__global__ __launch_bounds__(256) void k_w1t(const float* __restrict__ w1,
                                             float* __restrict__ w1t) {
    const int idx = blockIdx.x * 256 + threadIdx.x;
    const int hh = idx & 63;
    const int m = (idx >> 6) % NM;
    const int n = idx / (NM * 64);
    w1t[idx] = w1[(size_t)(m * 64 + hh) * ND + n];
}

// w2 (32,2,2048) -> w2t[n][c*32+i]
__global__ __launch_bounds__(256) void k_w2t(const float* __restrict__ w2,
                                             float* __restrict__ w2t) {
    const int idx = blockIdx.x * 256 + threadIdx.x;
    const int i = idx & 31;
    const int c = (idx >> 5) & 1;
    const int n = idx >> 6;
    w2t[idx] = w2[(size_t)(i * 2 + c) * ND + n];
}

// predTemp (B,T,O) -> out (B,O,T)
__global__ __launch_bounds__(256) void k_transpose(const float* __restrict__ predTemp,
                                                   float* __restrict__ out) {
    __shared__ float tile[NS * NITER];
    const int b = blockIdx.x >> 6;
    const int j0 = (blockIdx.x & 63) * 64;
    for (int i = threadIdx.x; i < 3200; i += 256) {
        const int tt = i >> 6, jj = i & 63;
        tile[jj * NITER + tt] = predTemp[((size_t)b * NITER + tt) * NOUT + j0 + jj];
    }
    __syncthreads();
    float* dst = out + ((size_t)b * NOUT + j0) * NITER;
    for (int i = threadIdx.x; i < 3200; i += 256) dst[i] = tile[i];
}

extern "C" void kernel_launch(void* const* d_in, const int* in_sizes, int n_in,
                              void* d_out, int out_size, void* d_ws, size_t ws_size,
                              hipStream_t stream) {
    const float* x        = (const float*)d_in[0];
    const float* kv_w     = (const float*)d_in[1];
    const float* kv_b     = (const float*)d_in[2];
    const float* kv_ln_g  = (const float*)d_in[3];
    const float* kv_ln_b  = (const float*)d_in[4];
    const float* q_w      = (const float*)d_in[5];
    const float* q_b      = (const float*)d_in[6];
    const float* wq       = (const float*)d_in[7];
    const float* wk       = (const float*)d_in[8];
    const float* wv       = (const float*)d_in[9];
    const float* wo       = (const float*)d_in[10];
    const float* bq       = (const float*)d_in[11];
    const float* bk       = (const float*)d_in[12];
    const float* bv       = (const float*)d_in[13];
    const float* bo       = (const float*)d_in[14];
    const float* syn_w    = (const float*)d_in[15];
    const float* syn_b    = (const float*)d_in[16];
    const float* syn_ln_g = (const float*)d_in[17];
    const float* syn_ln_b = (const float*)d_in[18];
    const float* nlm1_w   = (const float*)d_in[19];
    const float* nlm1_b   = (const float*)d_in[20];
    const float* nlm2_w   = (const float*)d_in[21];
    const float* nlm2_b   = (const float*)d_in[22];
    const float* start_a  = (const float*)d_in[23];
    const float* start_tr = (const float*)d_in[24];
    const float* dec_a    = (const float*)d_in[25];
    const float* dec_o    = (const float*)d_in[26];
    const float* out_w    = (const float*)d_in[27];
    const float* out_b    = (const float*)d_in[28];
    const int* ial        = (const int*)d_in[29];
    const int* iar        = (const int*)d_in[30];
    const int* iol        = (const int*)d_in[31];
    const int* ior        = (const int*)d_in[32];
    float* out = (float*)d_out;

    float* ws = (float*)d_ws;
    size_t off = 0;
    auto alloc = [&](size_t n) { float* p = ws + off; off += n; return p; };
    float* preT   = alloc((size_t)NKSYN * NB);          // 163840
    bf16_t* kp_t  = (bf16_t*)alloc((size_t)NB * NE * NS / 2);
    bf16_t* vp_t  = (bf16_t*)alloc((size_t)NB * NE * NS / 2);
    float* W_qq   = alloc((size_t)NE * NE);
    float* b_qq   = alloc(NE);
    float* r_a    = alloc(NE);
    float* r_o    = alloc(NE);
    float* aA     = alloc((size_t)NB * NE);             // zero span start
    float* bA     = alloc((size_t)NB * NE);
    float* aO     = alloc((size_t)2 * NB * NE);         // double-buffered
    float* bO     = alloc((size_t)2 * NB * NE);
    float* trace2 = alloc((size_t)NM * ND * NB);        // 3276800
    float* part   = alloc((size_t)8 * NB * NOUT);       // 2097152 (shared syn/out)
    float* w1t    = alloc((size_t)ND * NM * 64);        // 3276800
    float* w2t    = alloc((size_t)ND * 64);             // 131072
    int tmode = 0;
    float* predTemp = nullptr;
    if ((off + (size_t)PRED_TOTAL) * sizeof(float) <= ws_size) {
        predTemp = alloc((size_t)PRED_TOTAL);
        tmode = 1;
    }

    k_p0<<<1, 512, 0, stream>>>(dec_a, dec_o, q_b, wq, bq, r_a, r_o, b_qq);
    k_wqq<<<1024, 256, 0, stream>>>(q_w, wq, W_qq);
    k_init_trace2<<<(NM * ND * NB) / 256, 256, 0, stream>>>(start_tr, trace2);
    k_init_state<<<(INIT_TOTAL + 255) / 256, 256, 0, stream>>>(start_a, preT, aA);
    k_p1<<<NB * NS, 512, 0, stream>>>(x, kv_w, kv_b, kv_ln_g, kv_ln_b, wk, bk, wv, bv, kp_t, vp_t);
    k_w1t<<<(ND * NM * 64) / 256, 256, 0, stream>>>(nlm1_w, w1t);
    k_w2t<<<(ND * 64) / 256, 256, 0, stream>>>(nlm2_w, w2t);

    for (int t = 0; t < NITER; ++t) {
        k_front_final<<<NB, 512, 0, stream>>>(preT, aA, bA, r_a, ial, iar, W_qq, b_qq,
                                              kp_t, vp_t, wo, bo, part, out_b, out, predTemp,
                                              1, (t > 0) ? 1 : 0, t - 1, tmode);
        k_gemm_syn<<<256, 256, 0, stream>>>(preT, syn_w, part);
        k_glu_ln<<<NB, 256, 0, stream>>>(part, syn_b, syn_ln_g, syn_ln_b, trace2, t % NM);
        k_nlm<<<256, 256, 0, stream>>>(trace2, w1t, nlm1_b, w2t, nlm2_b, preT, t % NM);
        k_out<<<256, 256, 0, stream>>>(preT, aO, bO, r_o, iol, ior, out_w, part, t);
    }
    // final entropy/prediction for t = 49
    k_front_final<<<NB, 512, 0, stream>>>(preT, aA, bA, r_a, ial, iar, W_qq, b_qq,
                                          kp_t, vp_t, wo, bo, part, out_b, out, predTemp,
                                          0, 1, NITER - 1, tmode);
    if (tmode) k_transpose<<<NB * 64, 256, 0, stream>>>(predTemp, out);
}

// Round 6
// 10121.368 us; speedup vs baseline: 10.2311x; 1.3285x over previous
//
#include <hip/hip_runtime.h>
#include <math.h>

#define NB 64
#define ND 2048
#define NE 512
#define NM 25
#define NOUT 4096
#define NHEADS 8
#define NDH 64
#define NS 64
#define NITER 50
#define NKSYN 2560
#define PRED_TOTAL (NB * NOUT * NITER)   /* 13107200 */

typedef unsigned short bf16_t;

__device__ __forceinline__ float sigm(float x) { return 1.f / (1.f + expf(-x)); }

__device__ __forceinline__ bf16_t f2bf(float f) {
    unsigned u = __float_as_uint(f);
    unsigned r = (u + 0x7FFFu + ((u >> 16) & 1u)) >> 16;
    return (bf16_t)r;
}
__device__ __forceinline__ float bf2f(bf16_t h) {
    return __uint_as_float(((unsigned)h) << 16);
}

__device__ __forceinline__ float wredsum(float v) {
#pragma unroll
    for (int o = 32; o; o >>= 1) v += __shfl_xor(v, o);
    return v;
}
__device__ __forceinline__ float wredmax(float v) {
#pragma unroll
    for (int o = 32; o; o >>= 1) v = fmaxf(v, __shfl_xor(v, o));
    return v;
}

// OP: 0 = sum, 1 = max. red must hold >= blockDim.x/64 floats.
template <int OP>
__device__ __forceinline__ float blockReduce(float v, float* red) {
    const int tid = threadIdx.x, lane = tid & 63, wid = tid >> 6;
    v = (OP == 0) ? wredsum(v) : wredmax(v);
    __syncthreads();
    if (lane == 0) red[wid] = v;
    __syncthreads();
    if (tid == 0) {
        const int nw = blockDim.x >> 6;
        float r = red[0];
        for (int w = 1; w < nw; ++w) r = (OP == 0) ? r + red[w] : fmaxf(r, red[w]);
        red[0] = r;
    }
    __syncthreads();
    return red[0];
}

// ---------------- per-step kernels ----------------

// KA: [optional] final(tt) for prev step + front(it). grid 64 (b) x 512.
__global__ __launch_bounds__(512) void k_front_final(
        float* __restrict__ preT, float* __restrict__ aA, float* __restrict__ bA,
        const float* __restrict__ r_a,
        const int* __restrict__ ial, const int* __restrict__ iar,
        const float* __restrict__ W_qq, const float* __restrict__ b_qq,
        const bf16_t* __restrict__ kp_t, const bf16_t* __restrict__ vp_t,
        const float* __restrict__ wo, const float* __restrict__ bo,
        const float* __restrict__ part, const float* __restrict__ out_b,
        float* __restrict__ out, float* __restrict__ predTemp,
        int doFront, int doFinal, int tt, int tmode) {
    __shared__ float lds[2056];
    const int b = blockIdx.x;
    const int t = threadIdx.x;
    const int lane = t & 63, wv = t >> 6;
    float* red = lds + 2048;

    if (doFinal) {
        float pr[8];
        float lmax = -1e30f;
#pragma unroll
        for (int c = 0; c < 8; ++c) {
            const int j = t + c * 512;
            float v = out_b[j];
#pragma unroll
            for (int kp = 0; kp < 8; ++kp) v += part[((size_t)(kp * NB + b)) * NOUT + j];
            pr[c] = v;
            lmax = fmaxf(lmax, v);
        }
        const float mx = blockReduce<1>(lmax, red);
        float ls = 0.f;
#pragma unroll
        for (int c = 0; c < 8; ++c) ls += expf(pr[c] - mx);
        const float se = blockReduce<0>(ls, red);
        const float logZ = mx + logf(se);
        float le = 0.f;
#pragma unroll
        for (int c = 0; c < 8; ++c) { const float lp = pr[c] - logZ; le += expf(lp) * lp; }
        const float ent = blockReduce<0>(le, red);
        const float ne = -ent * 0.12022458674074694f;  // 1/ln(4096)
        if (tmode) {
#pragma unroll
            for (int c = 0; c < 8; ++c)
                predTemp[((size_t)b * NITER + tt) * NOUT + t + c * 512] = pr[c];
        } else {
#pragma unroll
            for (int c = 0; c < 8; ++c) {
                const int j = t + c * 512;
                out[((size_t)b * NOUT + j) * NITER + tt] = pr[c];
            }
        }
        if (t == 0) {
            out[PRED_TOTAL + b * 100 + tt] = ne;
            out[PRED_TOTAL + b * 100 + 50 + tt] = 1.f - ne;
        }
    }

    if (doFront) {
        float* syncS = lds;
        float* qhS = lds + 512;
        float* attnS = lds + 1024;
        float* oS = lds + 1536;
        if (doFinal) __syncthreads();
        // phase 1: action sync (stateful)
        {
            const int i = t;
            const float pl = preT[(NE + ial[i]) * NB + b];
            const float prr = preT[(NE + iar[i]) * NB + b];
            const float r = r_a[i];
            const float aN = r * aA[b * NE + i] + pl * prr;
            const float bN = r * bA[b * NE + i] + 1.f;
            aA[b * NE + i] = aN;
            bA[b * NE + i] = bN;
            syncS[i] = aN * rsqrtf(bN);
        }
        __syncthreads();
        // phase 2: qh = sync @ W_qq + b_qq
        {
            const int j = t;
            float acc = b_qq[j];
#pragma unroll 2
            for (int k = 0; k < NE; k += 4) {
                const float4 s4 = *(const float4*)(syncS + k);
                acc = fmaf(s4.x, W_qq[(k + 0) * NE + j], acc);
                acc = fmaf(s4.y, W_qq[(k + 1) * NE + j], acc);
                acc = fmaf(s4.z, W_qq[(k + 2) * NE + j], acc);
                acc = fmaf(s4.w, W_qq[(k + 3) * NE + j], acc);
            }
            qhS[j] = acc;
        }
        __syncthreads();
        // phase 3: scores + softmax (wave per head, lanes = s)
        {
            const int h = wv, s = lane;
            const bf16_t* kpp = kp_t + ((size_t)(b * NHEADS + h) * NDH) * NS + s;
            float sc = 0.f;
#pragma unroll 8
            for (int d = 0; d < NDH; ++d) sc = fmaf(qhS[h * NDH + d], bf2f(kpp[d * NS]), sc);
            sc *= 0.125f;
            const float mxv = wredmax(sc);
            const float ev = expf(sc - mxv);
            const float sm = wredsum(ev);
            attnS[h * NS + s] = ev / sm;
        }
        __syncthreads();
        // phase 4: o = attn @ V
        {
            const int h = wv, d = lane;
            const bf16_t* vpp = vp_t + ((size_t)(b * NHEADS + h) * NS) * NDH + d;
            float o = 0.f;
#pragma unroll 8
            for (int s2 = 0; s2 < NS; ++s2) o = fmaf(attnS[h * NS + s2], bf2f(vpp[s2 * NDH]), o);
            oS[h * NDH + d] = o;
        }
        __syncthreads();
        // phase 5: attn_out = o @ wo + bo -> preT rows [0,512)
        {
            const int j = t;
            float ao = bo[j];
#pragma unroll 2
            for (int e = 0; e < NE; e += 4) {
                const float4 o4 = *(const float4*)(oS + e);
                ao = fmaf(o4.x, wo[(e + 0) * NE + j], ao);
                ao = fmaf(o4.y, wo[(e + 1) * NE + j], ao);
                ao = fmaf(o4.z, wo[(e + 2) * NE + j], ao);
                ao = fmaf(o4.w, wo[(e + 3) * NE + j], ao);
            }
            preT[j * NB + b] = ao;
        }
    }
}

// KB: syn GEMM partials. grid 256 (kp=bid>>5, jt=bid&31) x 256.
// preT column operand is wave-uniform -> readfirstlane => s_load broadcast (no
// vector-load latency chain in the inner loop).
__global__ __launch_bounds__(256) void k_gemm_syn(const float* __restrict__ preT,
                                                  const float* __restrict__ syn_w,
                                                  float* __restrict__ part) {
    const int kp = blockIdx.x >> 5, jt = blockIdx.x & 31;
    const int j = jt * 128 + (threadIdx.x & 127);
    const int b0 = __builtin_amdgcn_readfirstlane((threadIdx.x >> 7) & 1) * 32;
    float acc[32];
#pragma unroll
    for (int q = 0; q < 32; ++q) acc[q] = 0.f;
    const int k0 = kp * 320;
    const float* __restrict__ pb = preT + b0;
#pragma unroll 2
    for (int k = k0; k < k0 + 320; ++k) {
        const float w = syn_w[(size_t)k * NOUT + j];
        const float* pk = pb + k * 64;          // uniform address -> scalar loads
#pragma unroll
        for (int q = 0; q < 32; ++q) acc[q] = fmaf(pk[q], w, acc[q]);
    }
#pragma unroll
    for (int q = 0; q < 32; ++q)
        part[((size_t)(kp * NB + b0 + q)) * NOUT + j] = acc[q];
}

// KC: reduce partials + GLU + LN -> trace2[pos]. grid 64 (b) x 256.
__global__ __launch_bounds__(256) void k_glu_ln(const float* __restrict__ part,
                                                const float* __restrict__ syn_b,
                                                const float* __restrict__ ln_g,
                                                const float* __restrict__ ln_b,
                                                float* __restrict__ trace2, int pos) {
    __shared__ float red[8];
    const int b = blockIdx.x;
    const int t = threadIdx.x;
    float g[8];
    float ssum = 0.f;
#pragma unroll
    for (int c = 0; c < 8; ++c) {
        const int n = t + c * 256;
        float ya = syn_b[n], yb = syn_b[n + ND];
#pragma unroll
        for (int kp = 0; kp < 8; ++kp) {
            ya += part[((size_t)(kp * NB + b)) * NOUT + n];
            yb += part[((size_t)(kp * NB + b)) * NOUT + n + ND];
        }
        g[c] = ya * sigm(yb);
        ssum += g[c];
    }
    const float mean = blockReduce<0>(ssum, red) * (1.f / ND);
    float vsum = 0.f;
#pragma unroll
    for (int c = 0; c < 8; ++c) { const float d = g[c] - mean; vsum += d * d; }
    const float var = blockReduce<0>(vsum, red) * (1.f / ND);
    const float rs = rsqrtf(var + 1e-5f);
#pragma unroll
    for (int c = 0; c < 8; ++c) {
        const int n = t + c * 256;
        const float st = (g[c] - mean) * rs * ln_g[n] + ln_b[n];
        trace2[((size_t)pos * ND + n) * NB + b] = st;
    }
}

// KD: per-neuron NLMs. grid 256 x 256. lane = b; n uniform per wave ->
// w1t/b1/w2t/b2 all scalar loads; trace2 vector load software-pipelined.
__global__ __launch_bounds__(256) void k_nlm(const float* __restrict__ trace2,
                                             const float* __restrict__ w1t,
                                             const float* __restrict__ b1,
                                             const float* __restrict__ w2t,
                                             const float* __restrict__ b2,
                                             float* __restrict__ preT, int pos) {
    const int b = threadIdx.x & 63;
    const int wvu = __builtin_amdgcn_readfirstlane(threadIdx.x >> 6);
#pragma unroll 1
    for (int sub = 0; sub < 2; ++sub) {
        const int n = blockIdx.x * 8 + wvu * 2 + sub;      // uniform
        const float* brow = b1 + n * 64;
        float acc[64];
#pragma unroll
        for (int q = 0; q < 64; ++q) acc[q] = brow[q];
        int phys = (pos + 1 < NM) ? pos + 1 : 0;
        float tr = trace2[((size_t)phys * ND + n) * NB + b];
#pragma unroll 1
        for (int m = 0; m < NM; ++m) {
            const int physN = (phys + 1 < NM) ? phys + 1 : 0;
            float trn = 0.f;
            if (m + 1 < NM) trn = trace2[((size_t)physN * ND + n) * NB + b];
            const float* wrow = w1t + ((size_t)n * NM + m) * 64;   // uniform -> s_load
#pragma unroll
            for (int q = 0; q < 64; ++q) acc[q] = fmaf(tr, wrow[q], acc[q]);
            tr = trn; phys = physN;
        }
        const float* w2r = w2t + n * 64;                            // uniform
        float z0 = b2[n * 2 + 0], z1 = b2[n * 2 + 1];
#pragma unroll
        for (int i = 0; i < 32; ++i) {
            const float hv = acc[i] * sigm(acc[32 + i]);
            z0 = fmaf(hv, w2r[i], z0);
            z1 = fmaf(hv, w2r[32 + i], z1);
        }
        preT[(NE + n) * NB + b] = z0 * sigm(z1);
    }
}

// KE: output sync + out GEMM partials. grid 256 (kp 8 x jt 32) x 256.
// GEMM: lane = b (conflict-free ds_read), out_w row uniform -> scalar loads.
__global__ __launch_bounds__(256) void k_out(const float* __restrict__ preT,
                                             float* __restrict__ aO, float* __restrict__ bO,
                                             const float* __restrict__ r_o,
                                             const int* __restrict__ iol,
                                             const int* __restrict__ ior,
                                             const float* __restrict__ out_w,
                                             float* __restrict__ part, int it) {
    __shared__ float syncL[4096];  // [64 k][64 b]
    const int kp = blockIdx.x >> 5, jt = blockIdx.x & 31;
    const int t = threadIdx.x;
    const int src = it & 1, dst = src ^ 1;
#pragma unroll
    for (int c = 0; c < 16; ++c) {
        const int idx = t + c * 256;
        const int il = idx >> 6, b = idx & 63;
        const int i = kp * 64 + il;
        const float pl = preT[(NE + iol[i]) * NB + b];
        const float prr = preT[(NE + ior[i]) * NB + b];
        const float r = r_o[i];
        const float aN = r * aO[src * 32768 + i * NB + b] + pl * prr;
        const float bN = r * bO[src * 32768 + i * NB + b] + 1.f;
        if (jt == 0) {
            aO[dst * 32768 + i * NB + b] = aN;
            bO[dst * 32768 + i * NB + b] = bN;
        }
        syncL[il * 64 + b] = aN * rsqrtf(bN);
    }
    __syncthreads();
    const int b = t & 63;
    const int j0 = jt * 128 + __builtin_amdgcn_readfirstlane(t >> 6) * 32;
    float acc[32];
#pragma unroll
    for (int q = 0; q < 32; ++q) acc[q] = 0.f;
#pragma unroll 2
    for (int k = 0; k < 64; ++k) {
        const float sv = syncL[k * 64 + b];
        const float* wrow = out_w + (size_t)(kp * 64 + k) * NOUT + j0;  // uniform
#pragma unroll
        for (int q = 0; q < 32; ++q) acc[q] = fmaf(sv, wrow[q], acc[q]);
    }
    float* dstp = part + ((size_t)(kp * NB + b)) * NOUT + j0;
#pragma unroll
    for (int q = 0; q < 32; ++q) dstp[q] = acc[q];
}

// ---------------- one-time precompute kernels ----------------

__global__ __launch_bounds__(512) void k_p0(const float* __restrict__ dec_a,
                                            const float* __restrict__ dec_o,
                                            const float* __restrict__ q_b,
                                            const float* __restrict__ wq,
                                            const float* __restrict__ bq,
                                            float* __restrict__ r_a, float* __restrict__ r_o,
                                            float* __restrict__ b_qq) {
    const int t = threadIdx.x;
    r_a[t] = expf(-fminf(fmaxf(dec_a[t], 0.f), 15.f));
    r_o[t] = expf(-fminf(fmaxf(dec_o[t], 0.f), 15.f));
    float acc = bq[t];
#pragma unroll 4
    for (int k = 0; k < NE; ++k) acc = fmaf(q_b[k], wq[k * NE + t], acc);
    b_qq[t] = acc;
}

// W_qq[r][c]: r uniform per block -> q_w scalar loads. grid 1024 x 256.
__global__ __launch_bounds__(256) void k_wqq(const float* __restrict__ q_w,
                                             const float* __restrict__ wq,
                                             float* __restrict__ W_qq) {
    const int r = blockIdx.x >> 1;
    const int c = ((blockIdx.x & 1) << 8) + threadIdx.x;
    float acc = 0.f;
#pragma unroll 4
    for (int k = 0; k < NE; ++k) acc = fmaf(q_w[r * NE + k], wq[k * NE + c], acc);
    W_qq[r * NE + c] = acc;
}

// trace2[m][n][b] = start_trace[n][m]
__global__ __launch_bounds__(256) void k_init_trace2(const float* __restrict__ st,
                                                     float* __restrict__ trace2) {
    const int idx = blockIdx.x * 256 + threadIdx.x;
    const int n = (idx >> 6) & (ND - 1);
    const int m = idx >> 17;
    trace2[idx] = st[n * NM + m];
}

// act init into preT rows [512,2560) + zero aA,bA,aO(x2),bO(x2) span (ceil-div).
#define INIT_TOTAL (NB * ND + 6 * NB * NE)
__global__ __launch_bounds__(256) void k_init_state(const float* __restrict__ sa,
                                                    float* __restrict__ preT,
                                                    float* __restrict__ zeroBase) {
    const int idx = blockIdx.x * 256 + threadIdx.x;
    if (idx >= INIT_TOTAL) return;
    if (idx < NB * ND) {
        const int b = idx & 63, n = idx >> 6;
        preT[(NE + n) * NB + b] = sa[n];
    } else {
        zeroBase[idx - NB * ND] = 0.f;
    }
}

// kv = LN(feats @ kv_w + kv_b); K/V projections -> bf16 caches
__global__ __launch_bounds__(512) void k_p1(const float* __restrict__ x,
                                            const float* __restrict__ kv_w,
                                            const float* __restrict__ kv_b,
                                            const float* __restrict__ ln_g,
                                            const float* __restrict__ ln_b,
                                            const float* __restrict__ wk,
                                            const float* __restrict__ bk,
                                            const float* __restrict__ wv,
                                            const float* __restrict__ bv,
                                            bf16_t* __restrict__ kp_t,
                                            bf16_t* __restrict__ vp_t) {
    __shared__ float kvS[NE];
    __shared__ float red[8];
    const int b = blockIdx.x >> 6, s = blockIdx.x & 63;
    const int e = threadIdx.x;
    float acc = kv_b[e];
#pragma unroll
    for (int c = 0; c < 12; ++c) acc = fmaf(x[b * 768 + c * 64 + s], kv_w[c * NE + e], acc);
    const float m = blockReduce<0>(acc, red) * (1.f / NE);
    const float d = acc - m;
    const float v = blockReduce<0>(d * d, red) * (1.f / NE);
    kvS[e] = d * rsqrtf(v + 1e-5f) * ln_g[e] + ln_b[e];
    __syncthreads();
    const int j = e;
    float kpv = bk[j], vpv = bv[j];
#pragma unroll 2
    for (int k = 0; k < NE; k += 4) {
        const float4 kv4 = *(const float4*)(kvS + k);
        kpv = fmaf(kv4.x, wk[(k + 0) * NE + j], kpv);
        kpv = fmaf(kv4.y, wk[(k + 1) * NE + j], kpv);
        kpv = fmaf(kv4.z, wk[(k + 2) * NE + j], kpv);
        kpv = fmaf(kv4.w, wk[(k + 3) * NE + j], kpv);
        vpv = fmaf(kv4.x, wv[(k + 0) * NE + j], vpv);
        vpv = fmaf(kv4.y, wv[(k + 1) * NE + j], vpv);
        vpv = fmaf(kv4.z, wv[(k + 2) * NE + j], vpv);
        vpv = fmaf(kv4.w, wv[(k + 3) * NE + j], vpv);
    }
    const int h = j >> 6, dd = j & 63;
    kp_t[((size_t)(b * NHEADS + h) * NDH + dd) * NS + s] = f2bf(kpv);
    vp_t[((size_t)(b * NHEADS + h) * NS + s) * NDH + dd] = f2bf(vpv);
}

// w1 (25,64,2048) -> w1t[n][m][hh], coalesced both sides via LDS tile.
// grid 800 (m 25 x ntile 32) x 256.
__global__ __launch_bounds__(256) void k_w1t(const float* __restrict__ w1,
                                             float* __restrict__ w1t) {
    __shared__ float tile[64][65];
    const int m = blockIdx.x >> 5, n0 = (blockIdx.x & 31) << 6;
    for (int i = threadIdx.x; i < 4096; i += 256) {
        const int hh = i >> 6, nn = i & 63;
        tile[hh][nn] = w1[(size_t)(m * 64 + hh) * ND + n0 + nn];
    }
    __syncthreads();
    for (int i = threadIdx.x; i < 4096; i += 256) {
        const int nn = i >> 6, hh = i & 63;
        w1t[((size_t)(n0 + nn) * NM + m) * 64 + hh] = tile[hh][nn];
    }
}

// w2 (32,2,2048) -> w2t[n][c*32+i]
__global__ __launch_bounds__(256) void k_w2t(const float* __restrict__ w2,
                                             float* __restrict__ w2t) {
    const int idx = blockIdx.x * 256 + threadIdx.x;
    const int i = idx & 31;
    const int c = (idx >> 5) & 1;
    const int n = idx >> 6;
    w2t[idx] = w2[(size_t)(i * 2 + c) * ND + n];
}

// predTemp (B,T,O) -> out (B,O,T)
__global__ __launch_bounds__(256) void k_transpose(const float* __restrict__ predTemp,
                                                   float* __restrict__ out) {
    __shared__ float tile[NS * NITER];
    const int b = blockIdx.x >> 6;
    const int j0 = (blockIdx.x & 63) * 64;
    for (int i = threadIdx.x; i < 3200; i += 256) {
        const int tt = i >> 6, jj = i & 63;
        tile[jj * NITER + tt] = predTemp[((size_t)b * NITER + tt) * NOUT + j0 + jj];
    }
    __syncthreads();
    float* dst = out + ((size_t)b * NOUT + j0) * NITER;
    for (int i = threadIdx.x; i < 3200; i += 256) dst[i] = tile[i];
}

extern "C" void kernel_launch(void* const* d_in, const int* in_sizes, int n_in,
                              void* d_out, int out_size, void* d_ws, size_t ws_size,
                              hipStream_t stream) {
    const float* x        = (const float*)d_in[0];
    const float* kv_w     = (const float*)d_in[1];
    const float* kv_b     = (const float*)d_in[2];
    const float* kv_ln_g  = (const float*)d_in[3];
    const float* kv_ln_b  = (const float*)d_in[4];
    const float* q_w      = (const float*)d_in[5];
    const float* q_b      = (const float*)d_in[6];
    const float* wq       = (const float*)d_in[7];
    const float* wk       = (const float*)d_in[8];
    const float* wv       = (const float*)d_in[9];
    const float* wo       = (const float*)d_in[10];
    const float* bq       = (const float*)d_in[11];
    const float* bk       = (const float*)d_in[12];
    const float* bv       = (const float*)d_in[13];
    const float* bo       = (const float*)d_in[14];
    const float* syn_w    = (const float*)d_in[15];
    const float* syn_b    = (const float*)d_in[16];
    const float* syn_ln_g = (const float*)d_in[17];
    const float* syn_ln_b = (const float*)d_in[18];
    const float* nlm1_w   = (const float*)d_in[19];
    const float* nlm1_b   = (const float*)d_in[20];
    const float* nlm2_w   = (const float*)d_in[21];
    const float* nlm2_b   = (const float*)d_in[22];
    const float* start_a  = (const float*)d_in[23];
    const float* start_tr = (const float*)d_in[24];
    const float* dec_a    = (const float*)d_in[25];
    const float* dec_o    = (const float*)d_in[26];
    const float* out_w    = (const float*)d_in[27];
    const float* out_b    = (const float*)d_in[28];
    const int* ial        = (const int*)d_in[29];
    const int* iar        = (const int*)d_in[30];
    const int* iol        = (const int*)d_in[31];
    const int* ior        = (const int*)d_in[32];
    float* out = (float*)d_out;

    float* ws = (float*)d_ws;
    size_t off = 0;
    auto alloc = [&](size_t n) { float* p = ws + off; off += n; return p; };
    float* preT   = alloc((size_t)NKSYN * NB);          // 163840
    bf16_t* kp_t  = (bf16_t*)alloc((size_t)NB * NE * NS / 2);
    bf16_t* vp_t  = (bf16_t*)alloc((size_t)NB * NE * NS / 2);
    float* W_qq   = alloc((size_t)NE * NE);
    float* b_qq   = alloc(NE);
    float* r_a    = alloc(NE);
    float* r_o    = alloc(NE);
    float* aA     = alloc((size_t)NB * NE);             // zero span start
    float* bA     = alloc((size_t)NB * NE);
    float* aO     = alloc((size_t)2 * NB * NE);         // double-buffered
    float* bO     = alloc((size_t)2 * NB * NE);
    float* trace2 = alloc((size_t)NM * ND * NB);        // 3276800
    float* part   = alloc((size_t)8 * NB * NOUT);       // 2097152 (shared syn/out)
    float* w1t    = alloc((size_t)ND * NM * 64);        // 3276800
    float* w2t    = alloc((size_t)ND * 64);             // 131072
    int tmode = 0;
    float* predTemp = nullptr;
    if ((off + (size_t)PRED_TOTAL) * sizeof(float) <= ws_size) {
        predTemp = alloc((size_t)PRED_TOTAL);
        tmode = 1;
    }

    k_p0<<<1, 512, 0, stream>>>(dec_a, dec_o, q_b, wq, bq, r_a, r_o, b_qq);
    k_wqq<<<1024, 256, 0, stream>>>(q_w, wq, W_qq);
    k_init_trace2<<<(NM * ND * NB) / 256, 256, 0, stream>>>(start_tr, trace2);
    k_init_state<<<(INIT_TOTAL + 255) / 256, 256, 0, stream>>>(start_a, preT, aA);
    k_p1<<<NB * NS, 512, 0, stream>>>(x, kv_w, kv_b, kv_ln_g, kv_ln_b, wk, bk, wv, bv, kp_t, vp_t);
    k_w1t<<<800, 256, 0, stream>>>(nlm1_w, w1t);
    k_w2t<<<(ND * 64) / 256, 256, 0, stream>>>(nlm2_w, w2t);

    for (int t = 0; t < NITER; ++t) {
        k_front_final<<<NB, 512, 0, stream>>>(preT, aA, bA, r_a, ial, iar, W_qq, b_qq,
                                              kp_t, vp_t, wo, bo, part, out_b, out, predTemp,
                                              1, (t > 0) ? 1 : 0, t - 1, tmode);
        k_gemm_syn<<<256, 256, 0, stream>>>(preT, syn_w, part);
        k_glu_ln<<<NB, 256, 0, stream>>>(part, syn_b, syn_ln_g, syn_ln_b, trace2, t % NM);
        k_nlm<<<256, 256, 0, stream>>>(trace2, w1t, nlm1_b, w2t, nlm2_b, preT, t % NM);
        k_out<<<256, 256, 0, stream>>>(preT, aO, bO, r_o, iol, ior, out_w, part, t);
    }
    // final entropy/prediction for t = 49
    k_front_final<<<NB, 512, 0, stream>>>(preT, aA, bA, r_a, ial, iar, W_qq, b_qq,
                                          kp_t, vp_t, wo, bo, part, out_b, out, predTemp,
                                          0, 1, NITER - 1, tmode);
    if (tmode) k_transpose<<<NB * 64, 256, 0, stream>>>(predTemp, out);
}

// Round 7
// 6709.454 us; speedup vs baseline: 15.4339x; 1.5085x over previous
//
#include <hip/hip_runtime.h>
#include <math.h>

#define NB 64
#define ND 2048
#define NE 512
#define NM 25
#define NOUT 4096
#define NHEADS 8
#define NDH 64
#define NS 64
#define NITER 50
#define NKSYN 2560
#define PRED_TOTAL (NB * NOUT * NITER)   /* 13107200 */

typedef unsigned short bf16_t;

__device__ __forceinline__ float sigm(float x) { return 1.f / (1.f + expf(-x)); }

__device__ __forceinline__ bf16_t f2bf(float f) {
    unsigned u = __float_as_uint(f);
    unsigned r = (u + 0x7FFFu + ((u >> 16) & 1u)) >> 16;
    return (bf16_t)r;
}
__device__ __forceinline__ float bf2f(bf16_t h) {
    return __uint_as_float(((unsigned)h) << 16);
}

__device__ __forceinline__ float wredsum(float v) {
#pragma unroll
    for (int o = 32; o; o >>= 1) v += __shfl_xor(v, o);
    return v;
}
__device__ __forceinline__ float wredmax(float v) {
#pragma unroll
    for (int o = 32; o; o >>= 1) v = fmaxf(v, __shfl_xor(v, o));
    return v;
}

// OP: 0 = sum, 1 = max. red must hold >= blockDim.x/64 floats.
template <int OP>
__device__ __forceinline__ float blockReduce(float v, float* red) {
    const int tid = threadIdx.x, lane = tid & 63, wid = tid >> 6;
    v = (OP == 0) ? wredsum(v) : wredmax(v);
    __syncthreads();
    if (lane == 0) red[wid] = v;
    __syncthreads();
    if (tid == 0) {
        const int nw = blockDim.x >> 6;
        float r = red[0];
        for (int w = 1; w < nw; ++w) r = (OP == 0) ? r + red[w] : fmaxf(r, red[w]);
        red[0] = r;
    }
    __syncthreads();
    return red[0];
}

// ---------------- per-step kernels ----------------

// KA: [optional] final(tt) for prev step + front(it). grid 64 (b) x 512.
__global__ __launch_bounds__(512) void k_front_final(
        float* __restrict__ preT, float* __restrict__ aA, float* __restrict__ bA,
        const float* __restrict__ r_a,
        const int* __restrict__ ial, const int* __restrict__ iar,
        const float* __restrict__ W_qq, const float* __restrict__ b_qq,
        const bf16_t* __restrict__ kp_t, const bf16_t* __restrict__ vp_t,
        const float* __restrict__ wo, const float* __restrict__ bo,
        const float* __restrict__ part, const float* __restrict__ out_b,
        float* __restrict__ out, float* __restrict__ predTemp,
        int doFront, int doFinal, int tt, int tmode) {
    __shared__ float lds[2056];
    const int b = blockIdx.x;
    const int t = threadIdx.x;
    const int lane = t & 63, wv = t >> 6;
    float* red = lds + 2048;

    if (doFinal) {
        float pr[8];
        float lmax = -1e30f;
#pragma unroll
        for (int c = 0; c < 8; ++c) {
            const int j = t + c * 512;
            float v = out_b[j];
#pragma unroll
            for (int kp = 0; kp < 8; ++kp) v += part[((size_t)(kp * NB + b)) * NOUT + j];
            pr[c] = v;
            lmax = fmaxf(lmax, v);
        }
        const float mx = blockReduce<1>(lmax, red);
        float ls = 0.f;
#pragma unroll
        for (int c = 0; c < 8; ++c) ls += expf(pr[c] - mx);
        const float se = blockReduce<0>(ls, red);
        const float logZ = mx + logf(se);
        float le = 0.f;
#pragma unroll
        for (int c = 0; c < 8; ++c) { const float lp = pr[c] - logZ; le += expf(lp) * lp; }
        const float ent = blockReduce<0>(le, red);
        const float ne = -ent * 0.12022458674074694f;  // 1/ln(4096)
        if (tmode) {
#pragma unroll
            for (int c = 0; c < 8; ++c)
                predTemp[((size_t)b * NITER + tt) * NOUT + t + c * 512] = pr[c];
        } else {
#pragma unroll
            for (int c = 0; c < 8; ++c) {
                const int j = t + c * 512;
                out[((size_t)b * NOUT + j) * NITER + tt] = pr[c];
            }
        }
        if (t == 0) {
            out[PRED_TOTAL + b * 100 + tt] = ne;
            out[PRED_TOTAL + b * 100 + 50 + tt] = 1.f - ne;
        }
    }

    if (doFront) {
        float* syncS = lds;
        float* qhS = lds + 512;
        float* attnS = lds + 1024;
        float* oS = lds + 1536;
        if (doFinal) __syncthreads();
        // phase 1: action sync (stateful)
        {
            const int i = t;
            const float pl = preT[(NE + ial[i]) * NB + b];
            const float prr = preT[(NE + iar[i]) * NB + b];
            const float r = r_a[i];
            const float aN = r * aA[b * NE + i] + pl * prr;
            const float bN = r * bA[b * NE + i] + 1.f;
            aA[b * NE + i] = aN;
            bA[b * NE + i] = bN;
            syncS[i] = aN * rsqrtf(bN);
        }
        __syncthreads();
        // phase 2: qh = sync @ W_qq + b_qq
        {
            const int j = t;
            float acc = b_qq[j];
#pragma unroll 4
            for (int k = 0; k < NE; k += 4) {
                const float4 s4 = *(const float4*)(syncS + k);
                acc = fmaf(s4.x, W_qq[(k + 0) * NE + j], acc);
                acc = fmaf(s4.y, W_qq[(k + 1) * NE + j], acc);
                acc = fmaf(s4.z, W_qq[(k + 2) * NE + j], acc);
                acc = fmaf(s4.w, W_qq[(k + 3) * NE + j], acc);
            }
            qhS[j] = acc;
        }
        __syncthreads();
        // phase 3: scores + softmax (wave per head, lanes = s)
        {
            const int h = wv, s = lane;
            const bf16_t* kpp = kp_t + ((size_t)(b * NHEADS + h) * NDH) * NS + s;
            float sc = 0.f;
#pragma unroll 8
            for (int d = 0; d < NDH; ++d) sc = fmaf(qhS[h * NDH + d], bf2f(kpp[d * NS]), sc);
            sc *= 0.125f;
            const float mxv = wredmax(sc);
            const float ev = expf(sc - mxv);
            const float sm = wredsum(ev);
            attnS[h * NS + s] = ev / sm;
        }
        __syncthreads();
        // phase 4: o = attn @ V
        {
            const int h = wv, d = lane;
            const bf16_t* vpp = vp_t + ((size_t)(b * NHEADS + h) * NS) * NDH + d;
            float o = 0.f;
#pragma unroll 8
            for (int s2 = 0; s2 < NS; ++s2) o = fmaf(attnS[h * NS + s2], bf2f(vpp[s2 * NDH]), o);
            oS[h * NDH + d] = o;
        }
        __syncthreads();
        // phase 5: attn_out = o @ wo + bo -> preT rows [0,512)
        {
            const int j = t;
            float ao = bo[j];
#pragma unroll 4
            for (int e = 0; e < NE; e += 4) {
                const float4 o4 = *(const float4*)(oS + e);
                ao = fmaf(o4.x, wo[(e + 0) * NE + j], ao);
                ao = fmaf(o4.y, wo[(e + 1) * NE + j], ao);
                ao = fmaf(o4.z, wo[(e + 2) * NE + j], ao);
                ao = fmaf(o4.w, wo[(e + 3) * NE + j], ao);
            }
            preT[j * NB + b] = ao;
        }
    }
}

// KB: syn GEMM partials. grid 512 (kp=bid>>6, jt=bid&63) x 256.
// 2 blocks/CU (= 2 waves/SIMD) for latency hiding; 16 acc/thread; preT column
// wave-uniform -> s_load broadcast.
__global__ __launch_bounds__(256) void k_gemm_syn(const float* __restrict__ preT,
                                                  const float* __restrict__ syn_w,
                                                  float* __restrict__ part) {
    const int kp = blockIdx.x >> 6, jt = blockIdx.x & 63;
    const int j = jt * 64 + (threadIdx.x & 63);
    const int b0 = __builtin_amdgcn_readfirstlane(threadIdx.x >> 6) * 16;
    float acc[16];
#pragma unroll
    for (int q = 0; q < 16; ++q) acc[q] = 0.f;
    const int k0 = kp * 320;
    const float* __restrict__ pb = preT + b0;
#pragma unroll 4
    for (int k = k0; k < k0 + 320; ++k) {
        const float w = syn_w[(size_t)k * NOUT + j];
        const float* pk = pb + k * 64;          // uniform address -> scalar loads
#pragma unroll
        for (int q = 0; q < 16; ++q) acc[q] = fmaf(pk[q], w, acc[q]);
    }
#pragma unroll
    for (int q = 0; q < 16; ++q)
        part[((size_t)(kp * NB + b0 + q)) * NOUT + j] = acc[q];
}

// KC: reduce partials + GLU + LN -> trace2[pos]. grid 64 (b) x 256.
__global__ __launch_bounds__(256) void k_glu_ln(const float* __restrict__ part,
                                                const float* __restrict__ syn_b,
                                                const float* __restrict__ ln_g,
                                                const float* __restrict__ ln_b,
                                                float* __restrict__ trace2, int pos) {
    __shared__ float red[8];
    const int b = blockIdx.x;
    const int t = threadIdx.x;
    float g[8];
    float ssum = 0.f;
#pragma unroll
    for (int c = 0; c < 8; ++c) {
        const int n = t + c * 256;
        float ya = syn_b[n], yb = syn_b[n + ND];
#pragma unroll
        for (int kp = 0; kp < 8; ++kp) {
            ya += part[((size_t)(kp * NB + b)) * NOUT + n];
            yb += part[((size_t)(kp * NB + b)) * NOUT + n + ND];
        }
        g[c] = ya * sigm(yb);
        ssum += g[c];
    }
    const float mean = blockReduce<0>(ssum, red) * (1.f / ND);
    float vsum = 0.f;
#pragma unroll
    for (int c = 0; c < 8; ++c) { const float d = g[c] - mean; vsum += d * d; }
    const float var = blockReduce<0>(vsum, red) * (1.f / ND);
    const float rs = rsqrtf(var + 1e-5f);
#pragma unroll
    for (int c = 0; c < 8; ++c) {
        const int n = t + c * 256;
        const float st = (g[c] - mean) * rs * ln_g[n] + ln_b[n];
        trace2[((size_t)pos * ND + n) * NB + b] = st;
    }
}

// KD: per-neuron NLMs. grid 512 x 256 (1 neuron per wave). lane = b; n uniform
// per wave -> w1t/b1/w2t/b2 scalar loads; trace2 vector load software-pipelined.
__global__ __launch_bounds__(256, 2) void k_nlm(const float* __restrict__ trace2,
                                                const float* __restrict__ w1t,
                                                const float* __restrict__ b1,
                                                const float* __restrict__ w2t,
                                                const float* __restrict__ b2,
                                                float* __restrict__ preT, int pos) {
    const int b = threadIdx.x & 63;
    const int wvu = __builtin_amdgcn_readfirstlane(threadIdx.x >> 6);
    const int n = blockIdx.x * 4 + wvu;                    // uniform per wave
    const float* brow = b1 + n * 64;
    float acc[64];
#pragma unroll
    for (int q = 0; q < 64; ++q) acc[q] = brow[q];
    int phys = (pos + 1 < NM) ? pos + 1 : 0;
    float tr = trace2[((size_t)phys * ND + n) * NB + b];
#pragma unroll 1
    for (int m = 0; m < NM; ++m) {
        const int physN = (phys + 1 < NM) ? phys + 1 : 0;
        float trn = 0.f;
        if (m + 1 < NM) trn = trace2[((size_t)physN * ND + n) * NB + b];
        const float* wrow = w1t + ((size_t)n * NM + m) * 64;   // uniform -> s_load
#pragma unroll
        for (int q = 0; q < 64; ++q) acc[q] = fmaf(tr, wrow[q], acc[q]);
        tr = trn; phys = physN;
    }
    const float* w2r = w2t + n * 64;                            // uniform
    float z0 = b2[n * 2 + 0], z1 = b2[n * 2 + 1];
#pragma unroll
    for (int i = 0; i < 32; ++i) {
        const float hv = acc[i] * sigm(acc[32 + i]);
        z0 = fmaf(hv, w2r[i], z0);
        z1 = fmaf(hv, w2r[32 + i], z1);
    }
    preT[(NE + n) * NB + b] = z0 * sigm(z1);
}

// KE: output sync + out GEMM partials. grid 512 (kp 8 x jt 64) x 256.
// GEMM: lane = b (conflict-free ds_read), out_w row uniform -> scalar loads.
__global__ __launch_bounds__(256) void k_out(const float* __restrict__ preT,
                                             float* __restrict__ aO, float* __restrict__ bO,
                                             const float* __restrict__ r_o,
                                             const int* __restrict__ iol,
                                             const int* __restrict__ ior,
                                             const float* __restrict__ out_w,
                                             float* __restrict__ part, int it) {
    __shared__ float syncL[4096];  // [64 k][64 b]
    const int kp = blockIdx.x >> 6, jt = blockIdx.x & 63;
    const int t = threadIdx.x;
    const int src = it & 1, dst = src ^ 1;
#pragma unroll
    for (int c = 0; c < 16; ++c) {
        const int idx = t + c * 256;
        const int il = idx >> 6, b = idx & 63;
        const int i = kp * 64 + il;
        const float pl = preT[(NE + iol[i]) * NB + b];
        const float prr = preT[(NE + ior[i]) * NB + b];
        const float r = r_o[i];
        const float aN = r * aO[src * 32768 + i * NB + b] + pl * prr;
        const float bN = r * bO[src * 32768 + i * NB + b] + 1.f;
        if (jt == 0) {
            aO[dst * 32768 + i * NB + b] = aN;
            bO[dst * 32768 + i * NB + b] = bN;
        }
        syncL[il * 64 + b] = aN * rsqrtf(bN);
    }
    __syncthreads();
    const int b = t & 63;
    const int j0 = jt * 64 + __builtin_amdgcn_readfirstlane(t >> 6) * 16;
    float acc[16];
#pragma unroll
    for (int q = 0; q < 16; ++q) acc[q] = 0.f;
#pragma unroll 4
    for (int k = 0; k < 64; ++k) {
        const float sv = syncL[k * 64 + b];
        const float* wrow = out_w + (size_t)(kp * 64 + k) * NOUT + j0;  // uniform
#pragma unroll
        for (int q = 0; q < 16; ++q) acc[q] = fmaf(sv, wrow[q], acc[q]);
    }
    float* dstp = part + ((size_t)(kp * NB + b)) * NOUT + j0;
#pragma unroll
    for (int q = 0; q < 16; ++q) dstp[q] = acc[q];
}

// ---------------- one-time precompute kernels ----------------

__global__ __launch_bounds__(512) void k_p0(const float* __restrict__ dec_a,
                                            const float* __restrict__ dec_o,
                                            const float* __restrict__ q_b,
                                            const float* __restrict__ wq,
                                            const float* __restrict__ bq,
                                            float* __restrict__ r_a, float* __restrict__ r_o,
                                            float* __restrict__ b_qq) {
    const int t = threadIdx.x;
    r_a[t] = expf(-fminf(fmaxf(dec_a[t], 0.f), 15.f));
    r_o[t] = expf(-fminf(fmaxf(dec_o[t], 0.f), 15.f));
    float acc = bq[t];
#pragma unroll 4
    for (int k = 0; k < NE; ++k) acc = fmaf(q_b[k], wq[k * NE + t], acc);
    b_qq[t] = acc;
}

// W_qq[r][c]: r uniform per block -> q_w scalar loads. grid 1024 x 256.
__global__ __launch_bounds__(256) void k_wqq(const float* __restrict__ q_w,
                                             const float* __restrict__ wq,
                                             float* __restrict__ W_qq) {
    const int r = blockIdx.x >> 1;
    const int c = ((blockIdx.x & 1) << 8) + threadIdx.x;
    float acc = 0.f;
#pragma unroll 4
    for (int k = 0; k < NE; ++k) acc = fmaf(q_w[r * NE + k], wq[k * NE + c], acc);
    W_qq[r * NE + c] = acc;
}

// trace2[m][n][b] = start_trace[n][m]
__global__ __launch_bounds__(256) void k_init_trace2(const float* __restrict__ st,
                                                     float* __restrict__ trace2) {
    const int idx = blockIdx.x * 256 + threadIdx.x;
    const int n = (idx >> 6) & (ND - 1);
    const int m = idx >> 17;
    trace2[idx] = st[n * NM + m];
}

// act init into preT rows [512,2560) + zero aA,bA,aO(x2),bO(x2) span (ceil-div).
#define INIT_TOTAL (NB * ND + 6 * NB * NE)
__global__ __launch_bounds__(256) void k_init_state(const float* __restrict__ sa,
                                                    float* __restrict__ preT,
                                                    float* __restrict__ zeroBase) {
    const int idx = blockIdx.x * 256 + threadIdx.x;
    if (idx >= INIT_TOTAL) return;
    if (idx < NB * ND) {
        const int b = idx & 63, n = idx >> 6;
        preT[(NE + n) * NB + b] = sa[n];
    } else {
        zeroBase[idx - NB * ND] = 0.f;
    }
}

// kv = LN(feats @ kv_w + kv_b); K/V projections -> bf16 caches
__global__ __launch_bounds__(512) void k_p1(const float* __restrict__ x,
                                            const float* __restrict__ kv_w,
                                            const float* __restrict__ kv_b,
                                            const float* __restrict__ ln_g,
                                            const float* __restrict__ ln_b,
                                            const float* __restrict__ wk,
                                            const float* __restrict__ bk,
                                            const float* __restrict__ wv,
                                            const float* __restrict__ bv,
                                            bf16_t* __restrict__ kp_t,
                                            bf16_t* __restrict__ vp_t) {
    __shared__ float kvS[NE];
    __shared__ float red[8];
    const int b = blockIdx.x >> 6, s = blockIdx.x & 63;
    const int e = threadIdx.x;
    float acc = kv_b[e];
#pragma unroll
    for (int c = 0; c < 12; ++c) acc = fmaf(x[b * 768 + c * 64 + s], kv_w[c * NE + e], acc);
    const float m = blockReduce<0>(acc, red) * (1.f / NE);
    const float d = acc - m;
    const float v = blockReduce<0>(d * d, red) * (1.f / NE);
    kvS[e] = d * rsqrtf(v + 1e-5f) * ln_g[e] + ln_b[e];
    __syncthreads();
    const int j = e;
    float kpv = bk[j], vpv = bv[j];
#pragma unroll 2
    for (int k = 0; k < NE; k += 4) {
        const float4 kv4 = *(const float4*)(kvS + k);
        kpv = fmaf(kv4.x, wk[(k + 0) * NE + j], kpv);
        kpv = fmaf(kv4.y, wk[(k + 1) * NE + j], kpv);
        kpv = fmaf(kv4.z, wk[(k + 2) * NE + j], kpv);
        kpv = fmaf(kv4.w, wk[(k + 3) * NE + j], kpv);
        vpv = fmaf(kv4.x, wv[(k + 0) * NE + j], vpv);
        vpv = fmaf(kv4.y, wv[(k + 1) * NE + j], vpv);
        vpv = fmaf(kv4.z, wv[(k + 2) * NE + j], vpv);
        vpv = fmaf(kv4.w, wv[(k + 3) * NE + j], vpv);
    }
    const int h = j >> 6, dd = j & 63;
    kp_t[((size_t)(b * NHEADS + h) * NDH + dd) * NS + s] = f2bf(kpv);
    vp_t[((size_t)(b * NHEADS + h) * NS + s) * NDH + dd] = f2bf(vpv);
}

// w1 (25,64,2048) -> w1t[n][m][hh], coalesced both sides via LDS tile.
// grid 800 (m 25 x ntile 32) x 256.
__global__ __launch_bounds__(256) void k_w1t(const float* __restrict__ w1,
                                             float* __restrict__ w1t) {
    __shared__ float tile[64][65];
    const int m = blockIdx.x >> 5, n0 = (blockIdx.x & 31) << 6;
    for (int i = threadIdx.x; i < 4096; i += 256) {
        const int hh = i >> 6, nn = i & 63;
        tile[hh][nn] = w1[(size_t)(m * 64 + hh) * ND + n0 + nn];
    }
    __syncthreads();
    for (int i = threadIdx.x; i < 4096; i += 256) {
        const int nn = i >> 6, hh = i & 63;
        w1t[((size_t)(n0 + nn) * NM + m) * 64 + hh] = tile[hh][nn];
    }
}

// w2 (32,2,2048) -> w2t[n][c*32+i]
__global__ __launch_bounds__(256) void k_w2t(const float* __restrict__ w2,
                                             float* __restrict__ w2t) {
    const int idx = blockIdx.x * 256 + threadIdx.x;
    const int i = idx & 31;
    const int c = (idx >> 5) & 1;
    const int n = idx >> 6;
    w2t[idx] = w2[(size_t)(i * 2 + c) * ND + n];
}

// predTemp (B,T,O) -> out (B,O,T)
__global__ __launch_bounds__(256) void k_transpose(const float* __restrict__ predTemp,
                                                   float* __restrict__ out) {
    __shared__ float tile[NS * NITER];
    const int b = blockIdx.x >> 6;
    const int j0 = (blockIdx.x & 63) * 64;
    for (int i = threadIdx.x; i < 3200; i += 256) {
        const int tt = i >> 6, jj = i & 63;
        tile[jj * NITER + tt] = predTemp[((size_t)b * NITER + tt) * NOUT + j0 + jj];
    }
    __syncthreads();
    float* dst = out + ((size_t)b * NOUT + j0) * NITER;
    for (int i = threadIdx.x; i < 3200; i += 256) dst[i] = tile[i];
}

extern "C" void kernel_launch(void* const* d_in, const int* in_sizes, int n_in,
                              void* d_out, int out_size, void* d_ws, size_t ws_size,
                              hipStream_t stream) {
    const float* x        = (const float*)d_in[0];
    const float* kv_w     = (const float*)d_in[1];
    const float* kv_b     = (const float*)d_in[2];
    const float* kv_ln_g  = (const float*)d_in[3];
    const float* kv_ln_b  = (const float*)d_in[4];
    const float* q_w      = (const float*)d_in[5];
    const float* q_b      = (const float*)d_in[6];
    const float* wq       = (const float*)d_in[7];
    const float* wk       = (const float*)d_in[8];
    const float* wv       = (const float*)d_in[9];
    const float* wo       = (const float*)d_in[10];
    const float* bq       = (const float*)d_in[11];
    const float* bk       = (const float*)d_in[12];
    const float* bv       = (const float*)d_in[13];
    const float* bo       = (const float*)d_in[14];
    const float* syn_w    = (const float*)d_in[15];
    const float* syn_b    = (const float*)d_in[16];
    const float* syn_ln_g = (const float*)d_in[17];
    const float* syn_ln_b = (const float*)d_in[18];
    const float* nlm1_w   = (const float*)d_in[19];
    const float* nlm1_b   = (const float*)d_in[20];
    const float* nlm2_w   = (const float*)d_in[21];
    const float* nlm2_b   = (const float*)d_in[22];
    const float* start_a  = (const float*)d_in[23];
    const float* start_tr = (const float*)d_in[24];
    const float* dec_a    = (const float*)d_in[25];
    const float* dec_o    = (const float*)d_in[26];
    const float* out_w    = (const float*)d_in[27];
    const float* out_b    = (const float*)d_in[28];
    const int* ial        = (const int*)d_in[29];
    const int* iar        = (const int*)d_in[30];
    const int* iol        = (const int*)d_in[31];
    const int* ior        = (const int*)d_in[32];
    float* out = (float*)d_out;

    float* ws = (float*)d_ws;
    size_t off = 0;
    auto alloc = [&](size_t n) { float* p = ws + off; off += n; return p; };
    float* preT   = alloc((size_t)NKSYN * NB);          // 163840
    bf16_t* kp_t  = (bf16_t*)alloc((size_t)NB * NE * NS / 2);
    bf16_t* vp_t  = (bf16_t*)alloc((size_t)NB * NE * NS / 2);
    float* W_qq   = alloc((size_t)NE * NE);
    float* b_qq   = alloc(NE);
    float* r_a    = alloc(NE);
    float* r_o    = alloc(NE);
    float* aA     = alloc((size_t)NB * NE);             // zero span start
    float* bA     = alloc((size_t)NB * NE);
    float* aO     = alloc((size_t)2 * NB * NE);         // double-buffered
    float* bO     = alloc((size_t)2 * NB * NE);
    float* trace2 = alloc((size_t)NM * ND * NB);        // 3276800
    float* part   = alloc((size_t)8 * NB * NOUT);       // 2097152 (shared syn/out)
    float* w1t    = alloc((size_t)ND * NM * 64);        // 3276800
    float* w2t    = alloc((size_t)ND * 64);             // 131072
    int tmode = 0;
    float* predTemp = nullptr;
    if ((off + (size_t)PRED_TOTAL) * sizeof(float) <= ws_size) {
        predTemp = alloc((size_t)PRED_TOTAL);
        tmode = 1;
    }

    k_p0<<<1, 512, 0, stream>>>(dec_a, dec_o, q_b, wq, bq, r_a, r_o, b_qq);
    k_wqq<<<1024, 256, 0, stream>>>(q_w, wq, W_qq);
    k_init_trace2<<<(NM * ND * NB) / 256, 256, 0, stream>>>(start_tr, trace2);
    k_init_state<<<(INIT_TOTAL + 255) / 256, 256, 0, stream>>>(start_a, preT, aA);
    k_p1<<<NB * NS, 512, 0, stream>>>(x, kv_w, kv_b, kv_ln_g, kv_ln_b, wk, bk, wv, bv, kp_t, vp_t);
    k_w1t<<<800, 256, 0, stream>>>(nlm1_w, w1t);
    k_w2t<<<(ND * 64) / 256, 256, 0, stream>>>(nlm2_w, w2t);

    for (int t = 0; t < NITER; ++t) {
        k_front_final<<<NB, 512, 0, stream>>>(preT, aA, bA, r_a, ial, iar, W_qq, b_qq,
                                              kp_t, vp_t, wo, bo, part, out_b, out, predTemp,
                                              1, (t > 0) ? 1 : 0, t - 1, tmode);
        k_gemm_syn<<<512, 256, 0, stream>>>(preT, syn_w, part);
        k_glu_ln<<<NB, 256, 0, stream>>>(part, syn_b, syn_ln_g, syn_ln_b, trace2, t % NM);
        k_nlm<<<512, 256, 0, stream>>>(trace2, w1t, nlm1_b, w2t, nlm2_b, preT, t % NM);
        k_out<<<512, 256, 0, stream>>>(preT, aO, bO, r_o, iol, ior, out_w, part, t);
    }
    // final entropy/prediction for t = 49
    k_front_final<<<NB, 512, 0, stream>>>(preT, aA, bA, r_a, ial, iar, W_qq, b_qq,
                                          kp_t, vp_t, wo, bo, part, out_b, out, predTemp,
                                          0, 1, NITER - 1, tmode);
    if (tmode) k_transpose<<<NB * 64, 256, 0, stream>>>(predTemp, out);
}

// Round 8
// 5835.244 us; speedup vs baseline: 17.7461x; 1.1498x over previous
//
#include <hip/hip_runtime.h>
#include <math.h>

#define NB 64
#define ND 2048
#define NE 512
#define NM 25
#define NOUT 4096
#define NHEADS 8
#define NDH 64
#define NS 64
#define NITER 50
#define NKSYN 2560
#define PRED_TOTAL (NB * NOUT * NITER)   /* 13107200 */

typedef unsigned short bf16_t;

__device__ __forceinline__ float sigm(float x) { return 1.f / (1.f + expf(-x)); }

__device__ __forceinline__ bf16_t f2bf(float f) {
    unsigned u = __float_as_uint(f);
    unsigned r = (u + 0x7FFFu + ((u >> 16) & 1u)) >> 16;
    return (bf16_t)r;
}
__device__ __forceinline__ float bf2f(bf16_t h) {
    return __uint_as_float(((unsigned)h) << 16);
}

__device__ __forceinline__ float wredsum(float v) {
#pragma unroll
    for (int o = 32; o; o >>= 1) v += __shfl_xor(v, o);
    return v;
}
__device__ __forceinline__ float wredmax(float v) {
#pragma unroll
    for (int o = 32; o; o >>= 1) v = fmaxf(v, __shfl_xor(v, o));
    return v;
}

template <int OP>
__device__ __forceinline__ float blockReduce(float v, float* red) {
    const int tid = threadIdx.x, lane = tid & 63, wid = tid >> 6;
    v = (OP == 0) ? wredsum(v) : wredmax(v);
    __syncthreads();
    if (lane == 0) red[wid] = v;
    __syncthreads();
    if (tid == 0) {
        const int nw = blockDim.x >> 6;
        float r = red[0];
        for (int w = 1; w < nw; ++w) r = (OP == 0) ? r + red[w] : fmaxf(r, red[w]);
        red[0] = r;
    }
    __syncthreads();
    return red[0];
}

// ---------------- per-step kernels ----------------

// KA: grid 256 (jt 4 x b 64) x 512.
// jt==0 blocks: final(tt) for prev step first. All blocks: sync_a (redundant,
// jt0 writes state dbuf) -> qh j-slice (k-split 4) -> attention for 2 own heads
// -> oT[e][b]. attn_out GEMV is algebraically folded into the syn GEMM (woSyn).
__global__ __launch_bounds__(512) void k_front_final(
        const float* __restrict__ actT, float* __restrict__ oT,
        float* __restrict__ aA, float* __restrict__ bA,
        const float* __restrict__ r_a,
        const int* __restrict__ ial, const int* __restrict__ iar,
        const float* __restrict__ W_qq, const float* __restrict__ b_qq,
        const bf16_t* __restrict__ kp_t, const bf16_t* __restrict__ vp_t,
        const float* __restrict__ part, const float* __restrict__ out_b,
        float* __restrict__ out, float* __restrict__ predTemp,
        int doFront, int doFinal, int tt, int tmode, int it) {
    __shared__ float syncS[512];
    __shared__ float partK[512];
    __shared__ float qhS[128];
    __shared__ float attnS[128];
    __shared__ float red[8];
    const int bid = blockIdx.x;
    const int jt = bid >> 6, b = bid & 63;
    const int t = threadIdx.x;
    const int lane = t & 63, wv = t >> 6;

    if (doFinal && jt == 0) {
        float pr[8];
        float lmax = -1e30f;
#pragma unroll
        for (int c = 0; c < 8; ++c) {
            const int j = t + c * 512;
            float v = out_b[j];
#pragma unroll
            for (int kp = 0; kp < 8; ++kp) v += part[((size_t)(kp * NB + b)) * NOUT + j];
            pr[c] = v;
            lmax = fmaxf(lmax, v);
        }
        const float mx = blockReduce<1>(lmax, red);
        float ls = 0.f;
#pragma unroll
        for (int c = 0; c < 8; ++c) ls += expf(pr[c] - mx);
        const float se = blockReduce<0>(ls, red);
        const float logZ = mx + logf(se);
        float le = 0.f;
#pragma unroll
        for (int c = 0; c < 8; ++c) { const float lp = pr[c] - logZ; le += expf(lp) * lp; }
        const float ent = blockReduce<0>(le, red);
        const float ne = -ent * 0.12022458674074694f;  // 1/ln(4096)
        if (tmode) {
#pragma unroll
            for (int c = 0; c < 8; ++c)
                predTemp[((size_t)b * NITER + tt) * NOUT + t + c * 512] = pr[c];
        } else {
#pragma unroll
            for (int c = 0; c < 8; ++c) {
                const int j = t + c * 512;
                out[((size_t)b * NOUT + j) * NITER + tt] = pr[c];
            }
        }
        if (t == 0) {
            out[PRED_TOTAL + b * 100 + tt] = ne;
            out[PRED_TOTAL + b * 100 + 50 + tt] = 1.f - ne;
        }
    }
    if (!doFront) return;

    const int src = it & 1, dst = src ^ 1;
    // phase 1: action sync (all blocks compute; jt0 persists new state)
    {
        const int i = t;
        const float pl = actT[ial[i] * NB + b];
        const float prr = actT[iar[i] * NB + b];
        const float r = r_a[i];
        const float aN = r * aA[src * 32768 + b * NE + i] + pl * prr;
        const float bN = r * bA[src * 32768 + b * NE + i] + 1.f;
        if (jt == 0) {
            aA[dst * 32768 + b * NE + i] = aN;
            bA[dst * 32768 + b * NE + i] = bN;
        }
        syncS[i] = aN * rsqrtf(bN);
    }
    __syncthreads();
    // phase 2: qh j-slice [jt*128, jt*128+128), k split 4-way
    {
        const int g = t >> 7, l = t & 127;
        const int j = jt * 128 + l;
        float acc = 0.f;
        const int kk0 = g * 128;
#pragma unroll 4
        for (int k = kk0; k < kk0 + 128; ++k)
            acc = fmaf(syncS[k], W_qq[k * NE + j], acc);
        partK[g * 128 + l] = acc;
    }
    __syncthreads();
    if (t < 128) {
        qhS[t] = b_qq[jt * 128 + t] + partK[t] + partK[128 + t] + partK[256 + t] + partK[384 + t];
    }
    __syncthreads();
    // phase 3: scores + softmax for heads 2jt, 2jt+1 (waves 0-1)
    if (wv < 2) {
        const int h = jt * 2 + wv, s = lane;
        const bf16_t* kpp = kp_t + ((size_t)(b * NHEADS + h) * NDH) * NS + s;
        float sc = 0.f;
#pragma unroll 8
        for (int d = 0; d < NDH; ++d) sc = fmaf(qhS[wv * 64 + d], bf2f(kpp[d * NS]), sc);
        sc *= 0.125f;
        const float mxv = wredmax(sc);
        const float ev = expf(sc - mxv);
        const float sm = wredsum(ev);
        attnS[wv * 64 + s] = ev / sm;
    }
    __syncthreads();
    // phase 4: o = attn @ V -> oT[e][b]
    if (wv < 2) {
        const int h = jt * 2 + wv, d = lane;
        const bf16_t* vpp = vp_t + ((size_t)(b * NHEADS + h) * NS) * NDH + d;
        float o = 0.f;
#pragma unroll 8
        for (int s2 = 0; s2 < NS; ++s2) o = fmaf(attnS[wv * 64 + s2], bf2f(vpp[s2 * NDH]), o);
        oT[(size_t)(h * NDH + d) * NB + b] = o;
    }
}

// KB: syn GEMM partials. grid 1024 (kp 16 x jt 64) x 256, 4 blocks/CU.
// k<512 rows come from oT/woSyn (wo folded), else actT/syn_w.
__global__ __launch_bounds__(256, 4) void k_gemm_syn(const float* __restrict__ oT,
                                                     const float* __restrict__ actT,
                                                     const float* __restrict__ woSyn,
                                                     const float* __restrict__ syn_w,
                                                     float* __restrict__ part) {
    const int kp = blockIdx.x >> 6, jt = blockIdx.x & 63;
    const int j = jt * 64 + (threadIdx.x & 63);
    const int b0 = __builtin_amdgcn_readfirstlane(threadIdx.x >> 6) * 16;
    float acc[16];
#pragma unroll
    for (int q = 0; q < 16; ++q) acc[q] = 0.f;
    const int k0 = kp * 160;
#pragma unroll 4
    for (int k = k0; k < k0 + 160; ++k) {
        const float w = (k < NE) ? woSyn[(size_t)k * NOUT + j]
                                 : syn_w[(size_t)k * NOUT + j];
        const float* pk = (k < NE) ? (oT + k * NB + b0)
                                   : (actT + (k - NE) * NB + b0);   // uniform -> s_load
#pragma unroll
        for (int q = 0; q < 16; ++q) acc[q] = fmaf(pk[q], w, acc[q]);
    }
#pragma unroll
    for (int q = 0; q < 16; ++q)
        part[((size_t)(kp * NB + b0 + q)) * NOUT + j] = acc[q];
}

// KC: reduce 16 partials + bias_eff + GLU + LN -> trace2[pos]. grid 64 x 256.
__global__ __launch_bounds__(256) void k_glu_ln(const float* __restrict__ part,
                                                const float* __restrict__ sbe,
                                                const float* __restrict__ ln_g,
                                                const float* __restrict__ ln_b,
                                                float* __restrict__ trace2, int pos) {
    __shared__ float red[8];
    const int b = blockIdx.x;
    const int t = threadIdx.x;
    float g[8];
    float ssum = 0.f;
#pragma unroll
    for (int c = 0; c < 8; ++c) {
        const int n = t + c * 256;
        float ya = sbe[n], yb = sbe[n + ND];
#pragma unroll
        for (int kp = 0; kp < 16; ++kp) {
            ya += part[((size_t)(kp * NB + b)) * NOUT + n];
            yb += part[((size_t)(kp * NB + b)) * NOUT + n + ND];
        }
        g[c] = ya * sigm(yb);
        ssum += g[c];
    }
    const float mean = blockReduce<0>(ssum, red) * (1.f / ND);
    float vsum = 0.f;
#pragma unroll
    for (int c = 0; c < 8; ++c) { const float d = g[c] - mean; vsum += d * d; }
    const float var = blockReduce<0>(vsum, red) * (1.f / ND);
    const float rs = rsqrtf(var + 1e-5f);
#pragma unroll
    for (int c = 0; c < 8; ++c) {
        const int n = t + c * 256;
        const float st = (g[c] - mean) * rs * ln_g[n] + ln_b[n];
        trace2[((size_t)pos * ND + n) * NB + b] = st;
    }
}

// KD: per-neuron NLMs -> actT. grid 512 x 256 (1 neuron per wave). lane = b.
__global__ __launch_bounds__(256, 2) void k_nlm(const float* __restrict__ trace2,
                                                const float* __restrict__ w1t,
                                                const float* __restrict__ b1,
                                                const float* __restrict__ w2t,
                                                const float* __restrict__ b2,
                                                float* __restrict__ actT, int pos) {
    const int b = threadIdx.x & 63;
    const int wvu = __builtin_amdgcn_readfirstlane(threadIdx.x >> 6);
    const int n = blockIdx.x * 4 + wvu;                    // uniform per wave
    const float* brow = b1 + n * 64;
    float acc[64];
#pragma unroll
    for (int q = 0; q < 64; ++q) acc[q] = brow[q];
    int phys = (pos + 1 < NM) ? pos + 1 : 0;
    float tr = trace2[((size_t)phys * ND + n) * NB + b];
#pragma unroll 1
    for (int m = 0; m < NM; ++m) {
        const int physN = (phys + 1 < NM) ? phys + 1 : 0;
        float trn = 0.f;
        if (m + 1 < NM) trn = trace2[((size_t)physN * ND + n) * NB + b];
        const float* wrow = w1t + ((size_t)n * NM + m) * 64;   // uniform -> s_load
#pragma unroll
        for (int q = 0; q < 64; ++q) acc[q] = fmaf(tr, wrow[q], acc[q]);
        tr = trn; phys = physN;
    }
    const float* w2r = w2t + n * 64;                            // uniform
    float z0 = b2[n * 2 + 0], z1 = b2[n * 2 + 1];
#pragma unroll
    for (int i = 0; i < 32; ++i) {
        const float hv = acc[i] * sigm(acc[32 + i]);
        z0 = fmaf(hv, w2r[i], z0);
        z1 = fmaf(hv, w2r[32 + i], z1);
    }
    actT[n * NB + b] = z0 * sigm(z1);
}

// KE: output sync + out GEMM partials. grid 512 (kp 8 x jt 64) x 256.
__global__ __launch_bounds__(256) void k_out(const float* __restrict__ actT,
                                             float* __restrict__ aO, float* __restrict__ bO,
                                             const float* __restrict__ r_o,
                                             const int* __restrict__ iol,
                                             const int* __restrict__ ior,
                                             const float* __restrict__ out_w,
                                             float* __restrict__ part, int it) {
    __shared__ float syncL[4096];  // [64 k][64 b]
    const int kp = blockIdx.x >> 6, jt = blockIdx.x & 63;
    const int t = threadIdx.x;
    const int src = it & 1, dst = src ^ 1;
#pragma unroll
    for (int c = 0; c < 16; ++c) {
        const int idx = t + c * 256;
        const int il = idx >> 6, b = idx & 63;
        const int i = kp * 64 + il;
        const float pl = actT[iol[i] * NB + b];
        const float prr = actT[ior[i] * NB + b];
        const float r = r_o[i];
        const float aN = r * aO[src * 32768 + i * NB + b] + pl * prr;
        const float bN = r * bO[src * 32768 + i * NB + b] + 1.f;
        if (jt == 0) {
            aO[dst * 32768 + i * NB + b] = aN;
            bO[dst * 32768 + i * NB + b] = bN;
        }
        syncL[il * 64 + b] = aN * rsqrtf(bN);
    }
    __syncthreads();
    const int b = t & 63;
    const int j0 = jt * 64 + __builtin_amdgcn_readfirstlane(t >> 6) * 16;
    float acc[16];
#pragma unroll
    for (int q = 0; q < 16; ++q) acc[q] = 0.f;
#pragma unroll 4
    for (int k = 0; k < 64; ++k) {
        const float sv = syncL[k * 64 + b];
        const float* wrow = out_w + (size_t)(kp * 64 + k) * NOUT + j0;  // uniform
#pragma unroll
        for (int q = 0; q < 16; ++q) acc[q] = fmaf(sv, wrow[q], acc[q]);
    }
    float* dstp = part + ((size_t)(kp * NB + b)) * NOUT + j0;
#pragma unroll
    for (int q = 0; q < 16; ++q) dstp[q] = acc[q];
}

// ---------------- one-time precompute kernels ----------------

__global__ __launch_bounds__(512) void k_p0(const float* __restrict__ dec_a,
                                            const float* __restrict__ dec_o,
                                            const float* __restrict__ q_b,
                                            const float* __restrict__ wq,
                                            const float* __restrict__ bq,
                                            float* __restrict__ r_a, float* __restrict__ r_o,
                                            float* __restrict__ b_qq) {
    const int t = threadIdx.x;
    r_a[t] = expf(-fminf(fmaxf(dec_a[t], 0.f), 15.f));
    r_o[t] = expf(-fminf(fmaxf(dec_o[t], 0.f), 15.f));
    float acc = bq[t];
#pragma unroll 4
    for (int k = 0; k < NE; ++k) acc = fmaf(q_b[k], wq[k * NE + t], acc);
    b_qq[t] = acc;
}

// W_qq[r][c]: r uniform per block -> q_w scalar loads. grid 1024 x 256.
__global__ __launch_bounds__(256) void k_wqq(const float* __restrict__ q_w,
                                             const float* __restrict__ wq,
                                             float* __restrict__ W_qq) {
    const int r = blockIdx.x >> 1;
    const int c = ((blockIdx.x & 1) << 8) + threadIdx.x;
    float acc = 0.f;
#pragma unroll 4
    for (int k = 0; k < NE; ++k) acc = fmaf(q_w[r * NE + k], wq[k * NE + c], acc);
    W_qq[r * NE + c] = acc;
}

// wo (512x512) -> woT[jp][e]. grid 64 (8x8 tiles) x 256.
__global__ __launch_bounds__(256) void k_woT(const float* __restrict__ wo,
                                             float* __restrict__ woT) {
    __shared__ float tile[64][65];
    const int te = blockIdx.x >> 3, tj = blockIdx.x & 7;
    for (int i = threadIdx.x; i < 4096; i += 256) {
        const int r = i >> 6, c = i & 63;   // r = e-local, c = jp-local
        tile[r][c] = wo[(size_t)(te * 64 + r) * NE + tj * 64 + c];
    }
    __syncthreads();
    for (int i = threadIdx.x; i < 4096; i += 256) {
        const int r = i >> 6, c = i & 63;   // r = jp-local, c = e-local
        woT[(size_t)(tj * 64 + r) * NE + te * 64 + c] = tile[c][r];
    }
}

// woSyn[e][c] = sum_jp wo[e][jp] * syn_w[jp][c]  (e<512, c<4096, jp<512).
// grid 512 (eg 8 x ct 64) x 256; woT rows scalar, syn_w rows coalesced.
__global__ __launch_bounds__(256) void k_woSyn(const float* __restrict__ woT,
                                               const float* __restrict__ syn_w,
                                               float* __restrict__ woSyn) {
    const int eg = blockIdx.x >> 6, ct = blockIdx.x & 63;
    const int c = ct * 64 + (threadIdx.x & 63);
    const int e0 = eg * 64 + __builtin_amdgcn_readfirstlane(threadIdx.x >> 6) * 16;
    float acc[16];
#pragma unroll
    for (int q = 0; q < 16; ++q) acc[q] = 0.f;
#pragma unroll 4
    for (int jp = 0; jp < NE; ++jp) {
        const float wv = syn_w[(size_t)jp * NOUT + c];
        const float* er = woT + (size_t)jp * NE + e0;      // uniform -> s_load
#pragma unroll
        for (int q = 0; q < 16; ++q) acc[q] = fmaf(er[q], wv, acc[q]);
    }
#pragma unroll
    for (int q = 0; q < 16; ++q)
        woSyn[(size_t)(e0 + q) * NOUT + c] = acc[q];
}

// syn_b_eff[c] = syn_b[c] + sum_jp bo[jp] * syn_w[jp][c]. grid 16 x 256.
__global__ __launch_bounds__(256) void k_sbe(const float* __restrict__ syn_b,
                                             const float* __restrict__ bo,
                                             const float* __restrict__ syn_w,
                                             float* __restrict__ sbe) {
    const int c = blockIdx.x * 256 + threadIdx.x;
    float acc = syn_b[c];
#pragma unroll 4
    for (int jp = 0; jp < NE; ++jp)
        acc = fmaf(bo[jp], syn_w[(size_t)jp * NOUT + c], acc);
    sbe[c] = acc;
}

// trace2[m][n][b] = start_trace[n][m]
__global__ __launch_bounds__(256) void k_init_trace2(const float* __restrict__ st,
                                                     float* __restrict__ trace2) {
    const int idx = blockIdx.x * 256 + threadIdx.x;
    const int n = (idx >> 6) & (ND - 1);
    const int m = idx >> 17;
    trace2[idx] = st[n * NM + m];
}

// actT init + zero aA(2),bA(2),aO(2),bO(2) contiguous span (ceil-div grid).
#define INIT_TOTAL (NB * ND + 8 * NB * NE)
__global__ __launch_bounds__(256) void k_init_state(const float* __restrict__ sa,
                                                    float* __restrict__ actT,
                                                    float* __restrict__ zeroBase) {
    const int idx = blockIdx.x * 256 + threadIdx.x;
    if (idx >= INIT_TOTAL) return;
    if (idx < NB * ND) {
        const int b = idx & 63, n = idx >> 6;
        actT[n * NB + b] = sa[n];
    } else {
        zeroBase[idx - NB * ND] = 0.f;
    }
}

// kv = LN(feats @ kv_w + kv_b); K/V projections -> bf16 caches
__global__ __launch_bounds__(512) void k_p1(const float* __restrict__ x,
                                            const float* __restrict__ kv_w,
                                            const float* __restrict__ kv_b,
                                            const float* __restrict__ ln_g,
                                            const float* __restrict__ ln_b,
                                            const float* __restrict__ wk,
                                            const float* __restrict__ bk,
                                            const float* __restrict__ wv,
                                            const float* __restrict__ bv,
                                            bf16_t* __restrict__ kp_t,
                                            bf16_t* __restrict__ vp_t) {
    __shared__ float kvS[NE];
    __shared__ float red[8];
    const int b = blockIdx.x >> 6, s = blockIdx.x & 63;
    const int e = threadIdx.x;
    float acc = kv_b[e];
#pragma unroll
    for (int c = 0; c < 12; ++c) acc = fmaf(x[b * 768 + c * 64 + s], kv_w[c * NE + e], acc);
    const float m = blockReduce<0>(acc, red) * (1.f / NE);
    const float d = acc - m;
    const float v = blockReduce<0>(d * d, red) * (1.f / NE);
    kvS[e] = d * rsqrtf(v + 1e-5f) * ln_g[e] + ln_b[e];
    __syncthreads();
    const int j = e;
    float kpv = bk[j], vpv = bv[j];
#pragma unroll 2
    for (int k = 0; k < NE; k += 4) {
        const float4 kv4 = *(const float4*)(kvS + k);
        kpv = fmaf(kv4.x, wk[(k + 0) * NE + j], kpv);
        kpv = fmaf(kv4.y, wk[(k + 1) * NE + j], kpv);
        kpv = fmaf(kv4.z, wk[(k + 2) * NE + j], kpv);
        kpv = fmaf(kv4.w, wk[(k + 3) * NE + j], kpv);
        vpv = fmaf(kv4.x, wv[(k + 0) * NE + j], vpv);
        vpv = fmaf(kv4.y, wv[(k + 1) * NE + j], vpv);
        vpv = fmaf(kv4.z, wv[(k + 2) * NE + j], vpv);
        vpv = fmaf(kv4.w, wv[(k + 3) * NE + j], vpv);
    }
    const int h = j >> 6, dd = j & 63;
    kp_t[((size_t)(b * NHEADS + h) * NDH + dd) * NS + s] = f2bf(kpv);
    vp_t[((size_t)(b * NHEADS + h) * NS + s) * NDH + dd] = f2bf(vpv);
}

// w1 (25,64,2048) -> w1t[n][m][hh], coalesced both sides via LDS tile.
__global__ __launch_bounds__(256) void k_w1t(const float* __restrict__ w1,
                                             float* __restrict__ w1t) {
    __shared__ float tile[64][65];
    const int m = blockIdx.x >> 5, n0 = (blockIdx.x & 31) << 6;
    for (int i = threadIdx.x; i < 4096; i += 256) {
        const int hh = i >> 6, nn = i & 63;
        tile[hh][nn] = w1[(size_t)(m * 64 + hh) * ND + n0 + nn];
    }
    __syncthreads();
    for (int i = threadIdx.x; i < 4096; i += 256) {
        const int nn = i >> 6, hh = i & 63;
        w1t[((size_t)(n0 + nn) * NM + m) * 64 + hh] = tile[hh][nn];
    }
}

// w2 (32,2,2048) -> w2t[n][c*32+i]
__global__ __launch_bounds__(256) void k_w2t(const float* __restrict__ w2,
                                             float* __restrict__ w2t) {
    const int idx = blockIdx.x * 256 + threadIdx.x;
    const int i = idx & 31;
    const int c = (idx >> 5) & 1;
    const int n = idx >> 6;
    w2t[idx] = w2[(size_t)(i * 2 + c) * ND + n];
}

// predTemp (B,T,O) -> out (B,O,T)
__global__ __launch_bounds__(256) void k_transpose(const float* __restrict__ predTemp,
                                                   float* __restrict__ out) {
    __shared__ float tile[NS * NITER];
    const int b = blockIdx.x >> 6;
    const int j0 = (blockIdx.x & 63) * 64;
    for (int i = threadIdx.x; i < 3200; i += 256) {
        const int tt = i >> 6, jj = i & 63;
        tile[jj * NITER + tt] = predTemp[((size_t)b * NITER + tt) * NOUT + j0 + jj];
    }
    __syncthreads();
    float* dst = out + ((size_t)b * NOUT + j0) * NITER;
    for (int i = threadIdx.x; i < 3200; i += 256) dst[i] = tile[i];
}

extern "C" void kernel_launch(void* const* d_in, const int* in_sizes, int n_in,
                              void* d_out, int out_size, void* d_ws, size_t ws_size,
                              hipStream_t stream) {
    const float* x        = (const float*)d_in[0];
    const float* kv_w     = (const float*)d_in[1];
    const float* kv_b     = (const float*)d_in[2];
    const float* kv_ln_g  = (const float*)d_in[3];
    const float* kv_ln_b  = (const float*)d_in[4];
    const float* q_w      = (const float*)d_in[5];
    const float* q_b      = (const float*)d_in[6];
    const float* wq       = (const float*)d_in[7];
    const float* wk       = (const float*)d_in[8];
    const float* wv       = (const float*)d_in[9];
    const float* wo       = (const float*)d_in[10];
    const float* bq       = (const float*)d_in[11];
    const float* bk       = (const float*)d_in[12];
    const float* bv       = (const float*)d_in[13];
    const float* bo       = (const float*)d_in[14];
    const float* syn_w    = (const float*)d_in[15];
    const float* syn_b    = (const float*)d_in[16];
    const float* syn_ln_g = (const float*)d_in[17];
    const float* syn_ln_b = (const float*)d_in[18];
    const float* nlm1_w   = (const float*)d_in[19];
    const float* nlm1_b   = (const float*)d_in[20];
    const float* nlm2_w   = (const float*)d_in[21];
    const float* nlm2_b   = (const float*)d_in[22];
    const float* start_a  = (const float*)d_in[23];
    const float* start_tr = (const float*)d_in[24];
    const float* dec_a    = (const float*)d_in[25];
    const float* dec_o    = (const float*)d_in[26];
    const float* out_w    = (const float*)d_in[27];
    const float* out_b    = (const float*)d_in[28];
    const int* ial        = (const int*)d_in[29];
    const int* iar        = (const int*)d_in[30];
    const int* iol        = (const int*)d_in[31];
    const int* ior        = (const int*)d_in[32];
    float* out = (float*)d_out;

    float* ws = (float*)d_ws;
    size_t off = 0;
    auto alloc = [&](size_t n) { float* p = ws + off; off += n; return p; };
    float* actT   = alloc((size_t)ND * NB);             // 131072
    float* oT     = alloc((size_t)NE * NB);             // 32768
    bf16_t* kp_t  = (bf16_t*)alloc((size_t)NB * NE * NS / 2);
    bf16_t* vp_t  = (bf16_t*)alloc((size_t)NB * NE * NS / 2);
    float* W_qq   = alloc((size_t)NE * NE);             // 262144
    float* woT    = alloc((size_t)NE * NE);             // 262144
    float* woSyn  = alloc((size_t)NE * NOUT);           // 2097152
    float* sbe    = alloc(NOUT);
    float* b_qq   = alloc(NE);
    float* r_a    = alloc(NE);
    float* r_o    = alloc(NE);
    float* aA     = alloc((size_t)2 * NB * NE);         // zero span start
    float* bA     = alloc((size_t)2 * NB * NE);
    float* aO     = alloc((size_t)2 * NB * NE);
    float* bO     = alloc((size_t)2 * NB * NE);
    float* trace2 = alloc((size_t)NM * ND * NB);        // 3276800
    float* part   = alloc((size_t)16 * NB * NOUT);      // 4194304
    float* w1t    = alloc((size_t)ND * NM * 64);        // 3276800
    float* w2t    = alloc((size_t)ND * 64);             // 131072
    int tmode = 0;
    float* predTemp = nullptr;
    if ((off + (size_t)PRED_TOTAL) * sizeof(float) <= ws_size) {
        predTemp = alloc((size_t)PRED_TOTAL);
        tmode = 1;
    }

    k_p0<<<1, 512, 0, stream>>>(dec_a, dec_o, q_b, wq, bq, r_a, r_o, b_qq);
    k_wqq<<<1024, 256, 0, stream>>>(q_w, wq, W_qq);
    k_woT<<<64, 256, 0, stream>>>(wo, woT);
    k_woSyn<<<512, 256, 0, stream>>>(woT, syn_w, woSyn);
    k_sbe<<<16, 256, 0, stream>>>(syn_b, bo, syn_w, sbe);
    k_init_trace2<<<(NM * ND * NB) / 256, 256, 0, stream>>>(start_tr, trace2);
    k_init_state<<<(INIT_TOTAL + 255) / 256, 256, 0, stream>>>(start_a, actT, aA);
    k_p1<<<NB * NS, 512, 0, stream>>>(x, kv_w, kv_b, kv_ln_g, kv_ln_b, wk, bk, wv, bv, kp_t, vp_t);
    k_w1t<<<800, 256, 0, stream>>>(nlm1_w, w1t);
    k_w2t<<<(ND * 64) / 256, 256, 0, stream>>>(nlm2_w, w2t);

    for (int t = 0; t < NITER; ++t) {
        k_front_final<<<256, 512, 0, stream>>>(actT, oT, aA, bA, r_a, ial, iar, W_qq, b_qq,
                                               kp_t, vp_t, part, out_b, out, predTemp,
                                               1, (t > 0) ? 1 : 0, t - 1, tmode, t);
        k_gemm_syn<<<1024, 256, 0, stream>>>(oT, actT, woSyn, syn_w, part);
        k_glu_ln<<<NB, 256, 0, stream>>>(part, sbe, syn_ln_g, syn_ln_b, trace2, t % NM);
        k_nlm<<<512, 256, 0, stream>>>(trace2, w1t, nlm1_b, w2t, nlm2_b, actT, t % NM);
        k_out<<<512, 256, 0, stream>>>(actT, aO, bO, r_o, iol, ior, out_w, part, t);
    }
    // final entropy/prediction for t = 49
    k_front_final<<<256, 512, 0, stream>>>(actT, oT, aA, bA, r_a, ial, iar, W_qq, b_qq,
                                           kp_t, vp_t, part, out_b, out, predTemp,
                                           0, 1, NITER - 1, tmode, NITER);
    if (tmode) k_transpose<<<NB * 64, 256, 0, stream>>>(predTemp, out);
}